// Round 2
// baseline (456.087 us; speedup 1.0000x reference)
//
#include <hip/hip_runtime.h>
#include <hip/hip_bf16.h>

// ---------- types ----------
typedef __attribute__((ext_vector_type(8))) short short8;   // 8 bf16 (4 VGPRs) MFMA A/B frag
typedef __attribute__((ext_vector_type(4))) float f32x4;    // MFMA C/D frag / float4
typedef __attribute__((ext_vector_type(2))) float f32x2;

static __device__ __forceinline__ unsigned short f2b(float f) {
    unsigned int v = __float_as_uint(f);
    unsigned int r = (v + 0x7FFFu + ((v >> 16) & 1u)) >> 16;   // RNE
    return (unsigned short)r;
}

template<int V> struct FVec;
template<> struct FVec<4> { using T = f32x4; };
template<> struct FVec<2> { using T = f32x2; };

// ---------- CSR build ----------
__global__ void k_init_cnt(int* cnt, int n) {
    int i = blockIdx.x * 256 + threadIdx.x;
    if (i < n) cnt[i] = 1;  // self-loop
}

__global__ void k_hist(const int* __restrict__ dst, int* __restrict__ cnt, int E) {
    int e = blockIdx.x * 256 + threadIdx.x;
    if (e < E) atomicAdd(&cnt[dst[e]], 1);
}

// single-block scan: rowptr[0]=0, rowptr[i+1]=inclusive sum of cnt[0..i]
__global__ __launch_bounds__(1024) void k_scan(const int* __restrict__ cnt, int* __restrict__ rowptr, int n) {
    __shared__ int ssum[1024];
    int t = threadIdx.x;
    int per = (n + 1023) / 1024;
    int beg = t * per, end = min(beg + per, n);
    int s = 0;
    for (int i = beg; i < end; i++) s += cnt[i];
    ssum[t] = s;
    __syncthreads();
    for (int off = 1; off < 1024; off <<= 1) {
        int v = (t >= off) ? ssum[t - off] : 0;
        __syncthreads();
        ssum[t] += v;
        __syncthreads();
    }
    int run = (t == 0) ? 0 : ssum[t - 1];
    if (t == 0) rowptr[0] = 0;
    for (int i = beg; i < end; i++) { run += cnt[i]; rowptr[i + 1] = run; }
}

__global__ void k_self(const int* __restrict__ rowptr, int* __restrict__ colidx, int* __restrict__ fill, int n) {
    int i = blockIdx.x * 256 + threadIdx.x;
    if (i < n) { colidx[rowptr[i]] = i; fill[i] = 1; }
}

__global__ void k_scatter(const int* __restrict__ src, const int* __restrict__ dst,
                          const int* __restrict__ rowptr, int* __restrict__ fill,
                          int* __restrict__ colidx, int E) {
    int e = blockIdx.x * 256 + threadIdx.x;
    if (e < E) {
        int s = src[e], d = dst[e];
        int pos = atomicAdd(&fill[d], 1);
        colidx[rowptr[d] + pos] = s;
    }
}

// ---------- W transpose + cast (fp32 -> bf16): wt[n*K+k] = bf16(w[k*Nc+n]) ----------
__global__ void k_transpose(const float* __restrict__ w, unsigned short* __restrict__ wt,
                            int K, int Nc) {
    int i = blockIdx.x * 256 + threadIdx.x;
    if (i < K * Nc) {
        int k = i / Nc, n = i % Nc;
        wt[n * K + k] = f2b(w[i]);
    }
}

// ---------- MFMA GEMM: H[M,NC] = A[M,K] (fp32) * B[K,NC], B given as bf16 Bt[NC,K] ----------
// block = 256 threads = 4 waves; tile 64(M) x NC(full); BK = 32; fp32 accumulate, fp32 out
template<int NC>
__global__ __launch_bounds__(256) void k_gemm(const float* __restrict__ A,
                                              const unsigned short* __restrict__ Bt,
                                              float* __restrict__ H,
                                              int K) {
    __shared__ unsigned short As[64][40];   // 32 cols + pad (16B-aligned rows: 80B stride)
    __shared__ unsigned short Bs[NC][40];
    const int tid  = threadIdx.x;
    const int lane = tid & 63;
    const int wv   = tid >> 6;
    const int rowBase = blockIdx.x * 64;
    const int quad = lane >> 4;
    const int l16  = lane & 15;
    constexpr int NT = NC / 16;
    f32x4 acc[NT] = {};

    const int ar = tid >> 2;            // A staging row 0..63
    const int ak = (tid & 3) * 8;       // A staging k-chunk

    for (int kk = 0; kk < K; kk += 32) {
        // stage A: fp32 -> bf16
        {
            const float* ap = A + (size_t)(rowBase + ar) * K + kk + ak;
            f32x4 a0 = *(const f32x4*)ap;
            f32x4 a1 = *(const f32x4*)(ap + 4);
            short8 s;
#pragma unroll
            for (int v = 0; v < 4; v++) { s[v] = (short)f2b(a0[v]); s[4 + v] = (short)f2b(a1[v]); }
            *(short8*)&As[ar][ak] = s;
        }
        // stage B: bf16 copy, NC*4 chunks of 8
#pragma unroll
        for (int c = tid; c < NC * 4; c += 256) {
            int br = c >> 2, bk = (c & 3) * 8;
            *(short8*)&Bs[br][bk] = *(const short8*)(Bt + (size_t)br * K + kk + bk);
        }
        __syncthreads();
        short8 af = *(const short8*)&As[wv * 16 + l16][quad * 8];
#pragma unroll
        for (int nt = 0; nt < NT; nt++) {
            short8 bf = *(const short8*)&Bs[nt * 16 + l16][quad * 8];
            acc[nt] = __builtin_amdgcn_mfma_f32_16x16x32_bf16(af, bf, acc[nt], 0, 0, 0);
        }
        __syncthreads();
    }
#pragma unroll
    for (int nt = 0; nt < NT; nt++) {
        int gcol = nt * 16 + l16;
#pragma unroll
        for (int r = 0; r < 4; r++) {
            int grow = rowBase + wv * 16 + quad * 4 + r;
            H[(size_t)grow * NC + gcol] = acc[nt][r];
        }
    }
}

// ---------- per-node attention logits: als[i] = h[i].a_src, ald[i] = h[i].a_dst ----------
template<int DOUT>
__global__ __launch_bounds__(256) void k_al(const float* __restrict__ h,
                                            const float* __restrict__ asrc,
                                            const float* __restrict__ adst,
                                            float* __restrict__ als, float* __restrict__ ald, int N) {
    int node = blockIdx.x * 4 + (threadIdx.x >> 6);
    if (node >= N) return;
    int lane = threadIdx.x & 63;
    constexpr int V = DOUT / 64;
    using VT = typename FVec<V>::T;
    VT hv = *(const VT*)(h + (size_t)node * DOUT + lane * V);
    VT sv = *(const VT*)(asrc + lane * V);
    VT dv = *(const VT*)(adst + lane * V);
    float s = 0.f, d = 0.f;
#pragma unroll
    for (int v = 0; v < V; v++) { s += hv[v] * sv[v]; d += hv[v] * dv[v]; }
#pragma unroll
    for (int off = 32; off; off >>= 1) { s += __shfl_xor(s, off); d += __shfl_xor(d, off); }
    if (lane == 0) { als[node] = s; ald[node] = d; }
}

// ---------- edge softmax + weighted aggregation, one wave per dst node ----------
template<int DOUT, bool RELU>
__global__ __launch_bounds__(256) void k_edge(const float* __restrict__ h,
                                              const float* __restrict__ als,
                                              const float* __restrict__ ald,
                                              const int* __restrict__ rowptr,
                                              const int* __restrict__ colidx,
                                              const float* __restrict__ bias,
                                              float* __restrict__ out, int N) {
    int node = blockIdx.x * 4 + (threadIdx.x >> 6);
    if (node >= N) return;
    int lane = threadIdx.x & 63;
    int beg = rowptr[node], end = rowptr[node + 1];
    int deg = end - beg;
    float aldi = ald[node];

    // pass 1: max (lane-parallel over edges); lane j<64 also caches its edge
    float m = -1e30f;
    float e_lane = -1e30f;
    int   s_lane = 0;
    for (int j = lane; j < deg; j += 64) {
        int s = colidx[beg + j];
        float e = als[s] + aldi;
        e = e > 0.f ? e : 0.2f * e;
        if (j < 64) { e_lane = e; s_lane = s; }
        m = fmaxf(m, e);
    }
#pragma unroll
    for (int off = 32; off; off >>= 1) m = fmaxf(m, __shfl_xor(m, off));

    // pass 2: denom
    float dsum = (lane < deg) ? __expf(e_lane - m) : 0.f;
    for (int j = lane + 64; j < deg; j += 64) {
        int s = colidx[beg + j];
        float e = als[s] + aldi;
        e = e > 0.f ? e : 0.2f * e;
        dsum += __expf(e - m);
    }
#pragma unroll
    for (int off = 32; off; off >>= 1) dsum += __shfl_xor(dsum, off);
    float inv = 1.0f / dsum;
    float w_lane = (lane < deg) ? __expf(e_lane - m) * inv : 0.f;

    // pass 3: weighted gather-accumulate (serial over edges, broadcast w/s via shfl)
    constexpr int V = DOUT / 64;
    using VT = typename FVec<V>::T;
    float acc[V] = {};
    int lim = deg < 64 ? deg : 64;
    const size_t laneOff = (size_t)lane * V;
    for (int j = 0; j < lim; j++) {
        float wj = __shfl(w_lane, j);
        int   sj = __shfl(s_lane, j);
        VT hv = *(const VT*)(h + (size_t)sj * DOUT + laneOff);
#pragma unroll
        for (int v = 0; v < V; v++) acc[v] += wj * hv[v];
    }
    for (int j = 64; j < deg; j++) {   // rare overflow path (deg>64): uniform broadcast loads
        int sj = colidx[beg + j];
        float e = als[sj] + aldi;
        e = e > 0.f ? e : 0.2f * e;
        float wj = __expf(e - m) * inv;
        VT hv = *(const VT*)(h + (size_t)sj * DOUT + laneOff);
#pragma unroll
        for (int v = 0; v < V; v++) acc[v] += wj * hv[v];
    }

    VT bv = *(const VT*)(bias + laneOff);
    VT ov;
#pragma unroll
    for (int v = 0; v < V; v++) {
        float val = acc[v] + bv[v];
        if (RELU) val = fmaxf(val, 0.f);
        ov[v] = val;
    }
    *(VT*)(out + (size_t)node * DOUT + laneOff) = ov;
}

// ---------- launch ----------
extern "C" void kernel_launch(void* const* d_in, const int* in_sizes, int n_in,
                              void* d_out, int out_size, void* d_ws, size_t ws_size,
                              hipStream_t stream) {
    const int DIN = 128, DH = 256, DOUT = 128;
    const int N = in_sizes[0] / DIN;        // 40000
    const int E = in_sizes[1] / 2;          // 400000

    const float* x   = (const float*)d_in[0];
    const int*   ei  = (const int*)d_in[1];
    const float* W1  = (const float*)d_in[3];
    const float* as1 = (const float*)d_in[4];
    const float* ad1 = (const float*)d_in[5];
    const float* b1  = (const float*)d_in[6];
    const float* W2  = (const float*)d_in[7];
    const float* as2 = (const float*)d_in[8];
    const float* ad2 = (const float*)d_in[9];
    const float* b2  = (const float*)d_in[10];
    const float* W3  = (const float*)d_in[11];
    const float* as3 = (const float*)d_in[12];
    const float* ad3 = (const float*)d_in[13];
    const float* b3  = (const float*)d_in[14];
    float* outp = (float*)d_out;

    // workspace carve
    char* ws = (char*)d_ws;
    size_t off = 0;
    auto carve = [&](size_t bytes) { char* p = ws + off; off = (off + bytes + 255) & ~(size_t)255; return p; };
    float* hbuf = (float*)carve((size_t)N * DH * 4);       // 41 MB
    float* gbuf = (float*)carve((size_t)N * DH * 4);       // 41 MB
    float* als  = (float*)carve((size_t)N * 4);
    float* ald  = (float*)carve((size_t)N * 4);
    unsigned short* wt = (unsigned short*)carve((size_t)DH * DH * 2);
    int* cnt    = (int*)carve((size_t)N * 4);
    int* rowptr = (int*)carve((size_t)(N + 1) * 4);
    int* fill   = (int*)carve((size_t)N * 4);
    int* colidx = (int*)carve((size_t)(E + N) * 4);
    (void)ws_size; (void)n_in; (void)out_size;

    const int* e_src = ei;
    const int* e_dst = ei + E;

    // CSR build (identical every call; d_ws re-poisoned between launches)
    k_init_cnt<<<(N + 255) / 256, 256, 0, stream>>>(cnt, N);
    k_hist<<<(E + 255) / 256, 256, 0, stream>>>(e_dst, cnt, E);
    k_scan<<<1, 1024, 0, stream>>>(cnt, rowptr, N);
    k_self<<<(N + 255) / 256, 256, 0, stream>>>(rowptr, colidx, fill, N);
    k_scatter<<<(E + 255) / 256, 256, 0, stream>>>(e_src, e_dst, rowptr, fill, colidx, E);

    const int nblk4 = (N + 3) / 4;
    const int mblk  = N / 64;

    // ---- layer 1: x[N,128] @ W1[128,256] ----
    k_transpose<<<(DIN * DH + 255) / 256, 256, 0, stream>>>(W1, wt, DIN, DH);
    k_gemm<256><<<mblk, 256, 0, stream>>>(x, wt, hbuf, DIN);
    k_al<256><<<nblk4, 256, 0, stream>>>(hbuf, as1, ad1, als, ald, N);
    k_edge<256, true><<<nblk4, 256, 0, stream>>>(hbuf, als, ald, rowptr, colidx, b1, gbuf, N);

    // ---- layer 2: g[N,256] @ W2[256,256] ----
    k_transpose<<<(DH * DH + 255) / 256, 256, 0, stream>>>(W2, wt, DH, DH);
    k_gemm<256><<<mblk, 256, 0, stream>>>(gbuf, wt, hbuf, DH);
    k_al<256><<<nblk4, 256, 0, stream>>>(hbuf, as2, ad2, als, ald, N);
    k_edge<256, true><<<nblk4, 256, 0, stream>>>(hbuf, als, ald, rowptr, colidx, b2, gbuf, N);

    // ---- layer 3: g[N,256] @ W3[256,128] ----
    k_transpose<<<(DH * DOUT + 255) / 256, 256, 0, stream>>>(W3, wt, DH, DOUT);
    k_gemm<128><<<mblk, 256, 0, stream>>>(gbuf, wt, hbuf, DH);
    k_al<128><<<nblk4, 256, 0, stream>>>(hbuf, as3, ad3, als, ald, N);
    k_edge<128, false><<<nblk4, 256, 0, stream>>>(hbuf, als, ald, rowptr, colidx, b3, outp, N);
}

// Round 3
// 388.172 us; speedup vs baseline: 1.1750x; 1.1750x over previous
//
#include <hip/hip_runtime.h>
#include <hip/hip_bf16.h>
#include <type_traits>

// ---------- types ----------
typedef __attribute__((ext_vector_type(8))) short short8;   // 8 bf16 (4 VGPRs) MFMA A/B frag
typedef __attribute__((ext_vector_type(4))) float f32x4;    // MFMA C/D frag / float4
typedef __attribute__((ext_vector_type(2))) float f32x2;
typedef __attribute__((ext_vector_type(4))) unsigned short u16x4;
typedef __attribute__((ext_vector_type(2))) unsigned short u16x2;

static __device__ __forceinline__ unsigned short f2b(float f) {
    unsigned int v = __float_as_uint(f);
    unsigned int r = (v + 0x7FFFu + ((v >> 16) & 1u)) >> 16;   // RNE
    return (unsigned short)r;
}
static __device__ __forceinline__ float b2f(unsigned short u) {
    return __uint_as_float(((unsigned int)u) << 16);
}

template<int V> struct FVec;
template<> struct FVec<4> { using T = f32x4; };
template<> struct FVec<2> { using T = f32x2; };
template<int V> struct UVec;
template<> struct UVec<4> { using T = u16x4; };
template<> struct UVec<2> { using T = u16x2; };

// ---------- CSR build ----------
__global__ void k_init_cnt(int* cnt, int n) {
    int i = blockIdx.x * 256 + threadIdx.x;
    if (i < n) cnt[i] = 1;  // self-loop
}

__global__ void k_hist(const int* __restrict__ dst, int* __restrict__ cnt, int E) {
    int e = blockIdx.x * 256 + threadIdx.x;
    if (e < E) atomicAdd(&cnt[dst[e]], 1);
}

__global__ __launch_bounds__(1024) void k_scan(const int* __restrict__ cnt, int* __restrict__ rowptr, int n) {
    __shared__ int ssum[1024];
    int t = threadIdx.x;
    int per = (n + 1023) / 1024;
    int beg = t * per, end = min(beg + per, n);
    int s = 0;
    for (int i = beg; i < end; i++) s += cnt[i];
    ssum[t] = s;
    __syncthreads();
    for (int off = 1; off < 1024; off <<= 1) {
        int v = (t >= off) ? ssum[t - off] : 0;
        __syncthreads();
        ssum[t] += v;
        __syncthreads();
    }
    int run = (t == 0) ? 0 : ssum[t - 1];
    if (t == 0) rowptr[0] = 0;
    for (int i = beg; i < end; i++) { run += cnt[i]; rowptr[i + 1] = run; }
}

__global__ void k_self(const int* __restrict__ rowptr, int* __restrict__ colidx, int* __restrict__ fill, int n) {
    int i = blockIdx.x * 256 + threadIdx.x;
    if (i < n) { colidx[rowptr[i]] = i; fill[i] = 1; }
}

__global__ void k_scatter(const int* __restrict__ src, const int* __restrict__ dst,
                          const int* __restrict__ rowptr, int* __restrict__ fill,
                          int* __restrict__ colidx, int E) {
    int e = blockIdx.x * 256 + threadIdx.x;
    if (e < E) {
        int s = src[e], d = dst[e];
        int pos = atomicAdd(&fill[d], 1);
        colidx[rowptr[d] + pos] = s;
    }
}

// ---------- W transpose + cast (fp32 -> bf16): wt[n*K+k] = bf16(w[k*Nc+n]) ----------
__global__ void k_transpose(const float* __restrict__ w, unsigned short* __restrict__ wt,
                            int K, int Nc) {
    int i = blockIdx.x * 256 + threadIdx.x;
    if (i < K * Nc) {
        int k = i / Nc, n = i % Nc;
        wt[n * K + k] = f2b(w[i]);
    }
}

// ---------- MFMA GEMM + fused attention logits ----------
// H[M,NC] (bf16) = A[M,K] * B[K,NC];  als/ald[row] = H[row,:] . asrc/adst (fp32 acc)
// A is fp32 (layer 1 input) or bf16 (edge-layer outputs). B given transposed bf16 Bt[NC,K].
// block = 256 threads = 4 waves; tile 64(M) x NC(full); BK = 32
template<int NC, typename AT>
__global__ __launch_bounds__(256) void k_gemm(const AT* __restrict__ A,
                                              const unsigned short* __restrict__ Bt,
                                              unsigned short* __restrict__ H,
                                              const float* __restrict__ asrc,
                                              const float* __restrict__ adst,
                                              float* __restrict__ als,
                                              float* __restrict__ ald,
                                              int K) {
    __shared__ unsigned short As[64][40];   // 32 cols + pad
    __shared__ unsigned short Bs[NC][40];
    const int tid  = threadIdx.x;
    const int lane = tid & 63;
    const int wv   = tid >> 6;
    const int rowBase = blockIdx.x * 64;
    const int quad = lane >> 4;
    const int l16  = lane & 15;
    constexpr int NT = NC / 16;
    f32x4 acc[NT] = {};

    const int ar = tid >> 2;            // A staging row 0..63
    const int ak = (tid & 3) * 8;       // A staging k-chunk

    for (int kk = 0; kk < K; kk += 32) {
        // stage A
        if constexpr (std::is_same_v<AT, float>) {
            const float* ap = A + (size_t)(rowBase + ar) * K + kk + ak;
            f32x4 a0 = *(const f32x4*)ap;
            f32x4 a1 = *(const f32x4*)(ap + 4);
            short8 s;
#pragma unroll
            for (int v = 0; v < 4; v++) { s[v] = (short)f2b(a0[v]); s[4 + v] = (short)f2b(a1[v]); }
            *(short8*)&As[ar][ak] = s;
        } else {
            *(short8*)&As[ar][ak] = *(const short8*)(A + (size_t)(rowBase + ar) * K + kk + ak);
        }
        // stage B
#pragma unroll
        for (int c = tid; c < NC * 4; c += 256) {
            int br = c >> 2, bk = (c & 3) * 8;
            *(short8*)&Bs[br][bk] = *(const short8*)(Bt + (size_t)br * K + kk + bk);
        }
        __syncthreads();
        short8 af = *(const short8*)&As[wv * 16 + l16][quad * 8];
#pragma unroll
        for (int nt = 0; nt < NT; nt++) {
            short8 bf = *(const short8*)&Bs[nt * 16 + l16][quad * 8];
            acc[nt] = __builtin_amdgcn_mfma_f32_16x16x32_bf16(af, bf, acc[nt], 0, 0, 0);
        }
        __syncthreads();
    }

    // epilogue: store bf16 H + fused als/ald
    float avs[NT], avd[NT];
#pragma unroll
    for (int nt = 0; nt < NT; nt++) {
        int gcol = nt * 16 + l16;
        avs[nt] = asrc[gcol];
        avd[nt] = adst[gcol];
#pragma unroll
        for (int r = 0; r < 4; r++) {
            int grow = rowBase + wv * 16 + quad * 4 + r;
            H[(size_t)grow * NC + gcol] = f2b(acc[nt][r]);
        }
    }
#pragma unroll
    for (int r = 0; r < 4; r++) {
        float ps = 0.f, pd = 0.f;
#pragma unroll
        for (int nt = 0; nt < NT; nt++) { ps += acc[nt][r] * avs[nt]; pd += acc[nt][r] * avd[nt]; }
#pragma unroll
        for (int off = 8; off; off >>= 1) { ps += __shfl_xor(ps, off); pd += __shfl_xor(pd, off); }
        if (l16 == 0) {
            int grow = rowBase + wv * 16 + quad * 4 + r;
            als[grow] = ps;
            ald[grow] = pd;
        }
    }
}

// ---------- edge softmax + weighted aggregation, one wave per dst node ----------
// h is bf16; accumulate fp32; OutT = unsigned short (bf16, layers 1-2) or float (layer 3)
template<int DOUT, bool RELU, typename OutT>
__global__ __launch_bounds__(256) void k_edge(const unsigned short* __restrict__ h,
                                              const float* __restrict__ als,
                                              const float* __restrict__ ald,
                                              const int* __restrict__ rowptr,
                                              const int* __restrict__ colidx,
                                              const float* __restrict__ bias,
                                              OutT* __restrict__ out, int N) {
    int node = blockIdx.x * 4 + (threadIdx.x >> 6);
    if (node >= N) return;
    int lane = threadIdx.x & 63;
    int beg = rowptr[node], end = rowptr[node + 1];
    int deg = end - beg;
    float aldi = ald[node];

    // pass 1: max; lanes j<64 cache their edge
    float m = -1e30f;
    float e_lane = -1e30f;
    int   s_lane = 0;
    for (int j = lane; j < deg; j += 64) {
        int s = colidx[beg + j];
        float e = als[s] + aldi;
        e = e > 0.f ? e : 0.2f * e;
        if (j < 64) { e_lane = e; s_lane = s; }
        m = fmaxf(m, e);
    }
#pragma unroll
    for (int off = 32; off; off >>= 1) m = fmaxf(m, __shfl_xor(m, off));

    // pass 2: denom
    float dsum = (lane < deg) ? __expf(e_lane - m) : 0.f;
    for (int j = lane + 64; j < deg; j += 64) {
        int s = colidx[beg + j];
        float e = als[s] + aldi;
        e = e > 0.f ? e : 0.2f * e;
        dsum += __expf(e - m);
    }
#pragma unroll
    for (int off = 32; off; off >>= 1) dsum += __shfl_xor(dsum, off);
    float inv = 1.0f / dsum;
    float w_lane = (lane < deg) ? __expf(e_lane - m) * inv : 0.f;

    // pass 3: weighted bf16 gather-accumulate
    constexpr int V = DOUT / 64;
    using UT = typename UVec<V>::T;
    float acc[V] = {};
    int lim = deg < 64 ? deg : 64;
    const size_t laneOff = (size_t)lane * V;
    for (int j = 0; j < lim; j++) {
        float wj = __shfl(w_lane, j);
        int   sj = __shfl(s_lane, j);
        UT hv = *(const UT*)(h + (size_t)sj * DOUT + laneOff);
#pragma unroll
        for (int v = 0; v < V; v++) acc[v] += wj * b2f(hv[v]);
    }
    for (int j = 64; j < deg; j++) {   // rare overflow path (deg>64)
        int sj = colidx[beg + j];
        float e = als[sj] + aldi;
        e = e > 0.f ? e : 0.2f * e;
        float wj = __expf(e - m) * inv;
        UT hv = *(const UT*)(h + (size_t)sj * DOUT + laneOff);
#pragma unroll
        for (int v = 0; v < V; v++) acc[v] += wj * b2f(hv[v]);
    }

    typename FVec<V>::T bv = *(const typename FVec<V>::T*)(bias + laneOff);
    if constexpr (std::is_same_v<OutT, float>) {
        typename FVec<V>::T ov;
#pragma unroll
        for (int v = 0; v < V; v++) {
            float val = acc[v] + bv[v];
            if (RELU) val = fmaxf(val, 0.f);
            ov[v] = val;
        }
        *(typename FVec<V>::T*)(out + (size_t)node * DOUT + laneOff) = ov;
    } else {
        UT ov;
#pragma unroll
        for (int v = 0; v < V; v++) {
            float val = acc[v] + bv[v];
            if (RELU) val = fmaxf(val, 0.f);
            ov[v] = f2b(val);
        }
        *(UT*)(out + (size_t)node * DOUT + laneOff) = ov;
    }
}

// ---------- launch ----------
extern "C" void kernel_launch(void* const* d_in, const int* in_sizes, int n_in,
                              void* d_out, int out_size, void* d_ws, size_t ws_size,
                              hipStream_t stream) {
    const int DIN = 128, DH = 256, DOUT = 128;
    const int N = in_sizes[0] / DIN;        // 40000
    const int E = in_sizes[1] / 2;          // 400000

    const float* x   = (const float*)d_in[0];
    const int*   ei  = (const int*)d_in[1];
    const float* W1  = (const float*)d_in[3];
    const float* as1 = (const float*)d_in[4];
    const float* ad1 = (const float*)d_in[5];
    const float* b1  = (const float*)d_in[6];
    const float* W2  = (const float*)d_in[7];
    const float* as2 = (const float*)d_in[8];
    const float* ad2 = (const float*)d_in[9];
    const float* b2  = (const float*)d_in[10];
    const float* W3  = (const float*)d_in[11];
    const float* as3 = (const float*)d_in[12];
    const float* ad3 = (const float*)d_in[13];
    const float* b3  = (const float*)d_in[14];
    float* outp = (float*)d_out;

    // workspace carve
    char* ws = (char*)d_ws;
    size_t off = 0;
    auto carve = [&](size_t bytes) { char* p = ws + off; off = (off + bytes + 255) & ~(size_t)255; return p; };
    unsigned short* hbuf = (unsigned short*)carve((size_t)N * DH * 2);  // 20 MB bf16
    unsigned short* gbuf = (unsigned short*)carve((size_t)N * DH * 2);  // 20 MB bf16
    float* als  = (float*)carve((size_t)N * 4);
    float* ald  = (float*)carve((size_t)N * 4);
    unsigned short* wt = (unsigned short*)carve((size_t)DH * DH * 2);
    int* cnt    = (int*)carve((size_t)N * 4);
    int* rowptr = (int*)carve((size_t)(N + 1) * 4);
    int* fill   = (int*)carve((size_t)N * 4);
    int* colidx = (int*)carve((size_t)(E + N) * 4);
    (void)ws_size; (void)n_in; (void)out_size;

    const int* e_src = ei;
    const int* e_dst = ei + E;

    // CSR build (identical every call)
    k_init_cnt<<<(N + 255) / 256, 256, 0, stream>>>(cnt, N);
    k_hist<<<(E + 255) / 256, 256, 0, stream>>>(e_dst, cnt, E);
    k_scan<<<1, 1024, 0, stream>>>(cnt, rowptr, N);
    k_self<<<(N + 255) / 256, 256, 0, stream>>>(rowptr, colidx, fill, N);
    k_scatter<<<(E + 255) / 256, 256, 0, stream>>>(e_src, e_dst, rowptr, fill, colidx, E);

    const int nblk4 = (N + 3) / 4;
    const int mblk  = N / 64;

    // ---- layer 1: x[N,128] @ W1[128,256] ----
    k_transpose<<<(DIN * DH + 255) / 256, 256, 0, stream>>>(W1, wt, DIN, DH);
    k_gemm<256, float><<<mblk, 256, 0, stream>>>(x, wt, hbuf, as1, ad1, als, ald, DIN);
    k_edge<256, true, unsigned short><<<nblk4, 256, 0, stream>>>(hbuf, als, ald, rowptr, colidx, b1, gbuf, N);

    // ---- layer 2: g[N,256] @ W2[256,256] ----
    k_transpose<<<(DH * DH + 255) / 256, 256, 0, stream>>>(W2, wt, DH, DH);
    k_gemm<256, unsigned short><<<mblk, 256, 0, stream>>>(gbuf, wt, hbuf, as2, ad2, als, ald, DH);
    k_edge<256, true, unsigned short><<<nblk4, 256, 0, stream>>>(hbuf, als, ald, rowptr, colidx, b2, gbuf, N);

    // ---- layer 3: g[N,256] @ W3[256,128] ----
    k_transpose<<<(DH * DOUT + 255) / 256, 256, 0, stream>>>(W3, wt, DH, DOUT);
    k_gemm<128, unsigned short><<<mblk, 256, 0, stream>>>(gbuf, wt, hbuf, as3, ad3, als, ald, DH);
    k_edge<128, false, float><<<nblk4, 256, 0, stream>>>(hbuf, als, ald, rowptr, colidx, b3, outp, N);
}

// Round 4
// 332.027 us; speedup vs baseline: 1.3736x; 1.1691x over previous
//
#include <hip/hip_runtime.h>
#include <hip/hip_bf16.h>
#include <type_traits>

// ---------- types ----------
typedef __attribute__((ext_vector_type(8))) short short8;   // 8 bf16 (4 VGPRs) MFMA A/B frag
typedef __attribute__((ext_vector_type(4))) float f32x4;    // MFMA C/D frag / float4
typedef __attribute__((ext_vector_type(2))) float f32x2;
typedef __attribute__((ext_vector_type(4))) unsigned short u16x4;
typedef __attribute__((ext_vector_type(2))) unsigned short u16x2;

static __device__ __forceinline__ unsigned short f2b(float f) {
    unsigned int v = __float_as_uint(f);
    unsigned int r = (v + 0x7FFFu + ((v >> 16) & 1u)) >> 16;   // RNE
    return (unsigned short)r;
}
static __device__ __forceinline__ float b2f(unsigned short u) {
    return __uint_as_float(((unsigned int)u) << 16);
}

template<int V> struct FVec;
template<> struct FVec<4> { using T = f32x4; };
template<> struct FVec<2> { using T = f32x2; };
template<int V> struct UVec;
template<> struct UVec<4> { using T = u16x4; };
template<> struct UVec<2> { using T = u16x2; };

// ---------- CSR build (unordered segment allocation — no prefix scan) ----------
__global__ void k_init_cnt(int* cnt, int* cursor, int n) {
    int i = blockIdx.x * 256 + threadIdx.x;
    if (i < n) cnt[i] = 1;  // self-loop
    if (i == 0) *cursor = 0;
}

__global__ void k_hist(const int* __restrict__ dst, int* __restrict__ cnt, int E) {
    int e = blockIdx.x * 256 + threadIdx.x;
    if (e < E) atomicAdd(&cnt[dst[e]], 1);
}

// per-node segment allocation: wave-scan of cnt + one atomicAdd per wave.
// Also places the self-loop and inits fill=1.
__global__ void k_assign(const int* __restrict__ cnt, int* __restrict__ begptr,
                         int* __restrict__ colidx, int* __restrict__ fill,
                         int* __restrict__ cursor, int n) {
    int i = blockIdx.x * 256 + threadIdx.x;
    int lane = threadIdx.x & 63;
    int c = (i < n) ? cnt[i] : 0;
    int s = c;  // inclusive wave scan
#pragma unroll
    for (int off = 1; off < 64; off <<= 1) {
        int v = __shfl_up(s, off);
        if (lane >= off) s += v;
    }
    int wavesum = __shfl(s, 63);
    int base = 0;
    if (lane == 63) base = atomicAdd(cursor, wavesum);
    base = __shfl(base, 63);
    int beg = base + s - c;
    if (i < n) { begptr[i] = beg; colidx[beg] = i; fill[i] = 1; }
}

__global__ void k_scatter(const int* __restrict__ src, const int* __restrict__ dst,
                          const int* __restrict__ begptr, int* __restrict__ fill,
                          int* __restrict__ colidx, int E) {
    int e = blockIdx.x * 256 + threadIdx.x;
    if (e < E) {
        int s = src[e], d = dst[e];
        int pos = atomicAdd(&fill[d], 1);
        colidx[begptr[d] + pos] = s;
    }
}

// ---------- W transpose + cast (fp32 -> bf16): wt[n*K+k] = bf16(w[k*Nc+n]) ----------
__global__ void k_transpose(const float* __restrict__ w, unsigned short* __restrict__ wt,
                            int K, int Nc) {
    int i = blockIdx.x * 256 + threadIdx.x;
    if (i < K * Nc) {
        int k = i / Nc, n = i % Nc;
        wt[n * K + k] = f2b(w[i]);
    }
}

// ---------- MFMA GEMM + fused attention logits ----------
// H[M,NC] (bf16) = A[M,K] * B[K,NC];  als/ald[row] = H[row,:] . asrc/adst (fp32 acc)
// A is fp32 (layer 1 input) or bf16 (edge-layer outputs). B given transposed bf16 Bt[NC,K].
// block = 256 threads = 4 waves; tile 64(M) x NC(full); BK = 32
template<int NC, typename AT>
__global__ __launch_bounds__(256) void k_gemm(const AT* __restrict__ A,
                                              const unsigned short* __restrict__ Bt,
                                              unsigned short* __restrict__ H,
                                              const float* __restrict__ asrc,
                                              const float* __restrict__ adst,
                                              float* __restrict__ als,
                                              float* __restrict__ ald,
                                              int K) {
    __shared__ unsigned short As[64][40];   // 32 cols + pad
    __shared__ unsigned short Bs[NC][40];
    const int tid  = threadIdx.x;
    const int lane = tid & 63;
    const int wv   = tid >> 6;
    const int rowBase = blockIdx.x * 64;
    const int quad = lane >> 4;
    const int l16  = lane & 15;
    constexpr int NT = NC / 16;
    f32x4 acc[NT] = {};

    const int ar = tid >> 2;            // A staging row 0..63
    const int ak = (tid & 3) * 8;       // A staging k-chunk

    for (int kk = 0; kk < K; kk += 32) {
        // stage A
        if constexpr (std::is_same_v<AT, float>) {
            const float* ap = A + (size_t)(rowBase + ar) * K + kk + ak;
            f32x4 a0 = *(const f32x4*)ap;
            f32x4 a1 = *(const f32x4*)(ap + 4);
            short8 s;
#pragma unroll
            for (int v = 0; v < 4; v++) { s[v] = (short)f2b(a0[v]); s[4 + v] = (short)f2b(a1[v]); }
            *(short8*)&As[ar][ak] = s;
        } else {
            *(short8*)&As[ar][ak] = *(const short8*)(A + (size_t)(rowBase + ar) * K + kk + ak);
        }
        // stage B
#pragma unroll
        for (int c = tid; c < NC * 4; c += 256) {
            int br = c >> 2, bk = (c & 3) * 8;
            *(short8*)&Bs[br][bk] = *(const short8*)(Bt + (size_t)br * K + kk + bk);
        }
        __syncthreads();
        short8 af = *(const short8*)&As[wv * 16 + l16][quad * 8];
#pragma unroll
        for (int nt = 0; nt < NT; nt++) {
            short8 bf = *(const short8*)&Bs[nt * 16 + l16][quad * 8];
            acc[nt] = __builtin_amdgcn_mfma_f32_16x16x32_bf16(af, bf, acc[nt], 0, 0, 0);
        }
        __syncthreads();
    }

    // epilogue: store bf16 H + fused als/ald
    float avs[NT], avd[NT];
#pragma unroll
    for (int nt = 0; nt < NT; nt++) {
        int gcol = nt * 16 + l16;
        avs[nt] = asrc[gcol];
        avd[nt] = adst[gcol];
#pragma unroll
        for (int r = 0; r < 4; r++) {
            int grow = rowBase + wv * 16 + quad * 4 + r;
            H[(size_t)grow * NC + gcol] = f2b(acc[nt][r]);
        }
    }
#pragma unroll
    for (int r = 0; r < 4; r++) {
        float ps = 0.f, pd = 0.f;
#pragma unroll
        for (int nt = 0; nt < NT; nt++) { ps += acc[nt][r] * avs[nt]; pd += acc[nt][r] * avd[nt]; }
#pragma unroll
        for (int off = 8; off; off >>= 1) { ps += __shfl_xor(ps, off); pd += __shfl_xor(pd, off); }
        if (l16 == 0) {
            int grow = rowBase + wv * 16 + quad * 4 + r;
            als[grow] = ps;
            ald[grow] = pd;
        }
    }
}

// ---------- edge softmax + weighted aggregation, one wave per dst node ----------
// h is bf16; accumulate fp32; OutT = unsigned short (bf16, layers 1-2) or float (layer 3)
template<int DOUT, bool RELU, typename OutT>
__global__ __launch_bounds__(256) void k_edge(const unsigned short* __restrict__ h,
                                              const float* __restrict__ als,
                                              const float* __restrict__ ald,
                                              const int* __restrict__ begptr,
                                              const int* __restrict__ cnt,
                                              const int* __restrict__ colidx,
                                              const float* __restrict__ bias,
                                              OutT* __restrict__ out, int N) {
    int node = blockIdx.x * 4 + (threadIdx.x >> 6);
    if (node >= N) return;
    int lane = threadIdx.x & 63;
    int beg = begptr[node];
    int deg = cnt[node];
    float aldi = ald[node];

    // pass 1: max; lanes j<64 cache their edge
    float m = -1e30f;
    float e_lane = -1e30f;
    int   s_lane = 0;
    for (int j = lane; j < deg; j += 64) {
        int s = colidx[beg + j];
        float e = als[s] + aldi;
        e = e > 0.f ? e : 0.2f * e;
        if (j < 64) { e_lane = e; s_lane = s; }
        m = fmaxf(m, e);
    }
#pragma unroll
    for (int off = 32; off; off >>= 1) m = fmaxf(m, __shfl_xor(m, off));

    // pass 2: denom
    float dsum = (lane < deg) ? __expf(e_lane - m) : 0.f;
    for (int j = lane + 64; j < deg; j += 64) {
        int s = colidx[beg + j];
        float e = als[s] + aldi;
        e = e > 0.f ? e : 0.2f * e;
        dsum += __expf(e - m);
    }
#pragma unroll
    for (int off = 32; off; off >>= 1) dsum += __shfl_xor(dsum, off);
    float inv = 1.0f / dsum;
    float w_lane = (lane < deg) ? __expf(e_lane - m) * inv : 0.f;

    // pass 3: weighted bf16 gather-accumulate
    constexpr int V = DOUT / 64;
    using UT = typename UVec<V>::T;
    float acc[V] = {};
    int lim = deg < 64 ? deg : 64;
    const size_t laneOff = (size_t)lane * V;
    for (int j = 0; j < lim; j++) {
        float wj = __shfl(w_lane, j);
        int   sj = __shfl(s_lane, j);
        UT hv = *(const UT*)(h + (size_t)sj * DOUT + laneOff);
#pragma unroll
        for (int v = 0; v < V; v++) acc[v] += wj * b2f(hv[v]);
    }
    for (int j = 64; j < deg; j++) {   // rare overflow path (deg>64)
        int sj = colidx[beg + j];
        float e = als[sj] + aldi;
        e = e > 0.f ? e : 0.2f * e;
        float wj = __expf(e - m) * inv;
        UT hv = *(const UT*)(h + (size_t)sj * DOUT + laneOff);
#pragma unroll
        for (int v = 0; v < V; v++) acc[v] += wj * b2f(hv[v]);
    }

    typename FVec<V>::T bv = *(const typename FVec<V>::T*)(bias + laneOff);
    if constexpr (std::is_same_v<OutT, float>) {
        typename FVec<V>::T ov;
#pragma unroll
        for (int v = 0; v < V; v++) {
            float val = acc[v] + bv[v];
            if (RELU) val = fmaxf(val, 0.f);
            ov[v] = val;
        }
        *(typename FVec<V>::T*)(out + (size_t)node * DOUT + laneOff) = ov;
    } else {
        UT ov;
#pragma unroll
        for (int v = 0; v < V; v++) {
            float val = acc[v] + bv[v];
            if (RELU) val = fmaxf(val, 0.f);
            ov[v] = f2b(val);
        }
        *(UT*)(out + (size_t)node * DOUT + laneOff) = ov;
    }
}

// ---------- launch ----------
extern "C" void kernel_launch(void* const* d_in, const int* in_sizes, int n_in,
                              void* d_out, int out_size, void* d_ws, size_t ws_size,
                              hipStream_t stream) {
    const int DIN = 128, DH = 256, DOUT = 128;
    const int N = in_sizes[0] / DIN;        // 40000
    const int E = in_sizes[1] / 2;          // 400000

    const float* x   = (const float*)d_in[0];
    const int*   ei  = (const int*)d_in[1];
    const float* W1  = (const float*)d_in[3];
    const float* as1 = (const float*)d_in[4];
    const float* ad1 = (const float*)d_in[5];
    const float* b1  = (const float*)d_in[6];
    const float* W2  = (const float*)d_in[7];
    const float* as2 = (const float*)d_in[8];
    const float* ad2 = (const float*)d_in[9];
    const float* b2  = (const float*)d_in[10];
    const float* W3  = (const float*)d_in[11];
    const float* as3 = (const float*)d_in[12];
    const float* ad3 = (const float*)d_in[13];
    const float* b3  = (const float*)d_in[14];
    float* outp = (float*)d_out;

    // workspace carve
    char* ws = (char*)d_ws;
    size_t off = 0;
    auto carve = [&](size_t bytes) { char* p = ws + off; off = (off + bytes + 255) & ~(size_t)255; return p; };
    unsigned short* hbuf = (unsigned short*)carve((size_t)N * DH * 2);  // 20 MB bf16
    unsigned short* gbuf = (unsigned short*)carve((size_t)N * DH * 2);  // 20 MB bf16
    float* als  = (float*)carve((size_t)N * 4);
    float* ald  = (float*)carve((size_t)N * 4);
    unsigned short* wt = (unsigned short*)carve((size_t)DH * DH * 2);
    int* cnt    = (int*)carve((size_t)N * 4);
    int* begptr = (int*)carve((size_t)N * 4);
    int* fill   = (int*)carve((size_t)N * 4);
    int* cursor = (int*)carve(256);
    int* colidx = (int*)carve((size_t)(E + N) * 4);
    (void)ws_size; (void)n_in; (void)out_size;

    const int* e_src = ei;
    const int* e_dst = ei + E;

    // CSR build (identical every call; segment order unimportant)
    k_init_cnt<<<(N + 255) / 256, 256, 0, stream>>>(cnt, cursor, N);
    k_hist<<<(E + 255) / 256, 256, 0, stream>>>(e_dst, cnt, E);
    k_assign<<<(N + 255) / 256, 256, 0, stream>>>(cnt, begptr, colidx, fill, cursor, N);
    k_scatter<<<(E + 255) / 256, 256, 0, stream>>>(e_src, e_dst, begptr, fill, colidx, E);

    const int nblk4 = (N + 3) / 4;
    const int mblk  = N / 64;

    // ---- layer 1: x[N,128] @ W1[128,256] ----
    k_transpose<<<(DIN * DH + 255) / 256, 256, 0, stream>>>(W1, wt, DIN, DH);
    k_gemm<256, float><<<mblk, 256, 0, stream>>>(x, wt, hbuf, as1, ad1, als, ald, DIN);
    k_edge<256, true, unsigned short><<<nblk4, 256, 0, stream>>>(hbuf, als, ald, begptr, cnt, colidx, b1, gbuf, N);

    // ---- layer 2: g[N,256] @ W2[256,256] ----
    k_transpose<<<(DH * DH + 255) / 256, 256, 0, stream>>>(W2, wt, DH, DH);
    k_gemm<256, unsigned short><<<mblk, 256, 0, stream>>>(gbuf, wt, hbuf, as2, ad2, als, ald, DH);
    k_edge<256, true, unsigned short><<<nblk4, 256, 0, stream>>>(hbuf, als, ald, begptr, cnt, colidx, b2, gbuf, N);

    // ---- layer 3: g[N,256] @ W3[256,128] ----
    k_transpose<<<(DH * DOUT + 255) / 256, 256, 0, stream>>>(W3, wt, DH, DOUT);
    k_gemm<128, unsigned short><<<mblk, 256, 0, stream>>>(gbuf, wt, hbuf, as3, ad3, als, ald, DH);
    k_edge<128, false, float><<<nblk4, 256, 0, stream>>>(hbuf, als, ald, begptr, cnt, colidx, b3, outp, N);
}

// Round 5
// 309.689 us; speedup vs baseline: 1.4727x; 1.0721x over previous
//
#include <hip/hip_runtime.h>
#include <hip/hip_bf16.h>
#include <type_traits>

// ---------- types ----------
typedef __attribute__((ext_vector_type(8))) short short8;   // 8 bf16 (4 VGPRs) MFMA A/B frag
typedef __attribute__((ext_vector_type(4))) float f32x4;    // MFMA C/D frag / float4
typedef __attribute__((ext_vector_type(2))) float f32x2;
typedef __attribute__((ext_vector_type(8))) float f32x8;
typedef __attribute__((ext_vector_type(8))) unsigned short u16x8;
typedef __attribute__((ext_vector_type(4))) unsigned short u16x4;
typedef __attribute__((ext_vector_type(2))) unsigned short u16x2;

static __device__ __forceinline__ unsigned short f2b(float f) {
    unsigned int v = __float_as_uint(f);
    unsigned int r = (v + 0x7FFFu + ((v >> 16) & 1u)) >> 16;   // RNE
    return (unsigned short)r;
}
static __device__ __forceinline__ float b2f(unsigned short u) {
    return __uint_as_float(((unsigned int)u) << 16);
}

template<int V> struct FVec;
template<> struct FVec<8> { using T = f32x8; };
template<> struct FVec<4> { using T = f32x4; };
template<> struct FVec<2> { using T = f32x2; };
template<int V> struct UVec;
template<> struct UVec<8> { using T = u16x8; };
template<> struct UVec<4> { using T = u16x4; };
template<> struct UVec<2> { using T = u16x2; };

// ---------- CSR build (unordered segment allocation — no prefix scan) ----------
__global__ void k_init_cnt(int* cnt, int* cursor, int n) {
    int i = blockIdx.x * 256 + threadIdx.x;
    if (i < n) cnt[i] = 1;  // self-loop
    if (i == 0) *cursor = 0;
}

__global__ void k_hist(const int* __restrict__ dst, int* __restrict__ cnt, int E) {
    int e = blockIdx.x * 256 + threadIdx.x;
    if (e < E) atomicAdd(&cnt[dst[e]], 1);
}

// per-node segment allocation: wave-scan of cnt + one atomicAdd per wave.
// Also places the self-loop and inits fill=1.
__global__ void k_assign(const int* __restrict__ cnt, int* __restrict__ begptr,
                         int* __restrict__ colidx, int* __restrict__ fill,
                         int* __restrict__ cursor, int n) {
    int i = blockIdx.x * 256 + threadIdx.x;
    int lane = threadIdx.x & 63;
    int c = (i < n) ? cnt[i] : 0;
    int s = c;  // inclusive wave scan
#pragma unroll
    for (int off = 1; off < 64; off <<= 1) {
        int v = __shfl_up(s, off);
        if (lane >= off) s += v;
    }
    int wavesum = __shfl(s, 63);
    int base = 0;
    if (lane == 63) base = atomicAdd(cursor, wavesum);
    base = __shfl(base, 63);
    int beg = base + s - c;
    if (i < n) { begptr[i] = beg; colidx[beg] = i; fill[i] = 1; }
}

__global__ void k_scatter(const int* __restrict__ src, const int* __restrict__ dst,
                          const int* __restrict__ begptr, int* __restrict__ fill,
                          int* __restrict__ colidx, int E) {
    int e = blockIdx.x * 256 + threadIdx.x;
    if (e < E) {
        int s = src[e], d = dst[e];
        int pos = atomicAdd(&fill[d], 1);
        colidx[begptr[d] + pos] = s;
    }
}

// ---------- W transpose + cast (fp32 -> bf16): wt[n*K+k] = bf16(w[k*Nc+n]) ----------
__global__ void k_transpose(const float* __restrict__ w, unsigned short* __restrict__ wt,
                            int K, int Nc) {
    int i = blockIdx.x * 256 + threadIdx.x;
    if (i < K * Nc) {
        int k = i / Nc, n = i % Nc;
        wt[n * K + k] = f2b(w[i]);
    }
}

// ---------- MFMA GEMM + fused attention logits ----------
// H[M,NC] (bf16) = A[M,K] * B[K,NC];  als/ald[row] = H[row,:] . asrc/adst (fp32 acc)
// A is fp32 (layer 1 input) or bf16 (edge-layer outputs). B given transposed bf16 Bt[NC,K].
// block = 256 threads = 4 waves; tile 64(M) x NC(full); BK = 32
template<int NC, typename AT>
__global__ __launch_bounds__(256) void k_gemm(const AT* __restrict__ A,
                                              const unsigned short* __restrict__ Bt,
                                              unsigned short* __restrict__ H,
                                              const float* __restrict__ asrc,
                                              const float* __restrict__ adst,
                                              float* __restrict__ als,
                                              float* __restrict__ ald,
                                              int K) {
    __shared__ unsigned short As[64][40];   // 32 cols + pad
    __shared__ unsigned short Bs[NC][40];
    const int tid  = threadIdx.x;
    const int lane = tid & 63;
    const int wv   = tid >> 6;
    const int rowBase = blockIdx.x * 64;
    const int quad = lane >> 4;
    const int l16  = lane & 15;
    constexpr int NT = NC / 16;
    f32x4 acc[NT] = {};

    const int ar = tid >> 2;            // A staging row 0..63
    const int ak = (tid & 3) * 8;       // A staging k-chunk

    for (int kk = 0; kk < K; kk += 32) {
        // stage A
        if constexpr (std::is_same_v<AT, float>) {
            const float* ap = A + (size_t)(rowBase + ar) * K + kk + ak;
            f32x4 a0 = *(const f32x4*)ap;
            f32x4 a1 = *(const f32x4*)(ap + 4);
            short8 s;
#pragma unroll
            for (int v = 0; v < 4; v++) { s[v] = (short)f2b(a0[v]); s[4 + v] = (short)f2b(a1[v]); }
            *(short8*)&As[ar][ak] = s;
        } else {
            *(short8*)&As[ar][ak] = *(const short8*)(A + (size_t)(rowBase + ar) * K + kk + ak);
        }
        // stage B
#pragma unroll
        for (int c = tid; c < NC * 4; c += 256) {
            int br = c >> 2, bk = (c & 3) * 8;
            *(short8*)&Bs[br][bk] = *(const short8*)(Bt + (size_t)br * K + kk + bk);
        }
        __syncthreads();
        short8 af = *(const short8*)&As[wv * 16 + l16][quad * 8];
#pragma unroll
        for (int nt = 0; nt < NT; nt++) {
            short8 bf = *(const short8*)&Bs[nt * 16 + l16][quad * 8];
            acc[nt] = __builtin_amdgcn_mfma_f32_16x16x32_bf16(af, bf, acc[nt], 0, 0, 0);
        }
        __syncthreads();
    }

    // epilogue: store bf16 H + fused als/ald
    float avs[NT], avd[NT];
#pragma unroll
    for (int nt = 0; nt < NT; nt++) {
        int gcol = nt * 16 + l16;
        avs[nt] = asrc[gcol];
        avd[nt] = adst[gcol];
#pragma unroll
        for (int r = 0; r < 4; r++) {
            int grow = rowBase + wv * 16 + quad * 4 + r;
            H[(size_t)grow * NC + gcol] = f2b(acc[nt][r]);
        }
    }
#pragma unroll
    for (int r = 0; r < 4; r++) {
        float ps = 0.f, pd = 0.f;
#pragma unroll
        for (int nt = 0; nt < NT; nt++) { ps += acc[nt][r] * avs[nt]; pd += acc[nt][r] * avd[nt]; }
#pragma unroll
        for (int off = 8; off; off >>= 1) { ps += __shfl_xor(ps, off); pd += __shfl_xor(pd, off); }
        if (l16 == 0) {
            int grow = rowBase + wv * 16 + quad * 4 + r;
            als[grow] = ps;
            ald[grow] = pd;
        }
    }
}

// ---------- edge softmax + weighted aggregation, one wave per dst node ----------
// Pass 3 processes TWO edges per iteration: lanes 0-31 take edge 2t, lanes 32-63 edge 2t+1.
// Each lane covers DOUT/32 dims (16B loads at DH=256). h bf16; fp32 accumulate.
template<int DOUT, bool RELU, typename OutT>
__global__ __launch_bounds__(256) void k_edge(const unsigned short* __restrict__ h,
                                              const float* __restrict__ als,
                                              const float* __restrict__ ald,
                                              const int* __restrict__ begptr,
                                              const int* __restrict__ cnt,
                                              const int* __restrict__ colidx,
                                              const float* __restrict__ bias,
                                              OutT* __restrict__ out, int N) {
    int node = blockIdx.x * 4 + (threadIdx.x >> 6);
    if (node >= N) return;
    int lane = threadIdx.x & 63;
    int beg = begptr[node];
    int deg = cnt[node];
    float aldi = ald[node];

    // pass 1: max; lanes j<64 cache their edge
    float m = -1e30f;
    float e_lane = -1e30f;
    int   s_lane = 0;
    for (int j = lane; j < deg; j += 64) {
        int s = colidx[beg + j];
        float e = als[s] + aldi;
        e = e > 0.f ? e : 0.2f * e;
        if (j < 64) { e_lane = e; s_lane = s; }
        m = fmaxf(m, e);
    }
#pragma unroll
    for (int off = 32; off; off >>= 1) m = fmaxf(m, __shfl_xor(m, off));

    // pass 2: denom
    float dsum = (lane < deg) ? __expf(e_lane - m) : 0.f;
    for (int j = lane + 64; j < deg; j += 64) {
        int s = colidx[beg + j];
        float e = als[s] + aldi;
        e = e > 0.f ? e : 0.2f * e;
        dsum += __expf(e - m);
    }
#pragma unroll
    for (int off = 32; off; off >>= 1) dsum += __shfl_xor(dsum, off);
    float inv = 1.0f / dsum;
    float w_lane = (lane < deg) ? __expf(e_lane - m) * inv : 0.f;   // lane >= deg carries 0

    // pass 3: paired-edge weighted gather-accumulate
    constexpr int VH = DOUT / 32;          // dims per lane (8 @ DH=256, 4 @ DOUT=128)
    using UH = typename UVec<VH>::T;
    const int l32  = lane & 31;
    const int half = lane >> 5;
    const size_t dimOff = (size_t)l32 * VH;
    float acc[VH] = {};
    int lim = deg < 64 ? deg : 64;
    for (int t = 0; 2 * t < lim; t++) {
        int idx = 2 * t + half;            // lane deg (odd tail) holds w_lane==0 -> harmless
        float wj = __shfl(w_lane, idx);
        int   sj = __shfl(s_lane, idx);
        UH hv = *(const UH*)(h + (size_t)sj * DOUT + dimOff);
#pragma unroll
        for (int v = 0; v < VH; v++) acc[v] += wj * b2f(hv[v]);
    }
    for (int j = 64; j < deg; j++) {       // rare overflow path (deg>64): half 0 only
        int sj = colidx[beg + j];
        float e = als[sj] + aldi;
        e = e > 0.f ? e : 0.2f * e;
        float wj = __expf(e - m) * inv;
        if (half == 0) {
            UH hv = *(const UH*)(h + (size_t)sj * DOUT + dimOff);
#pragma unroll
            for (int v = 0; v < VH; v++) acc[v] += wj * b2f(hv[v]);
        }
    }
    // combine halves: both halves end up with the full sum
#pragma unroll
    for (int v = 0; v < VH; v++) acc[v] += __shfl_xor(acc[v], 32);

    if (half == 0) {
        typename FVec<VH>::T bv = *(const typename FVec<VH>::T*)(bias + dimOff);
        if constexpr (std::is_same_v<OutT, float>) {
            typename FVec<VH>::T ov;
#pragma unroll
            for (int v = 0; v < VH; v++) {
                float val = acc[v] + bv[v];
                if (RELU) val = fmaxf(val, 0.f);
                ov[v] = val;
            }
            *(typename FVec<VH>::T*)(out + (size_t)node * DOUT + dimOff) = ov;
        } else {
            UH ov;
#pragma unroll
            for (int v = 0; v < VH; v++) {
                float val = acc[v] + bv[v];
                if (RELU) val = fmaxf(val, 0.f);
                ov[v] = f2b(val);
            }
            *(UH*)(out + (size_t)node * DOUT + dimOff) = ov;
        }
    }
}

// ---------- launch ----------
extern "C" void kernel_launch(void* const* d_in, const int* in_sizes, int n_in,
                              void* d_out, int out_size, void* d_ws, size_t ws_size,
                              hipStream_t stream) {
    const int DIN = 128, DH = 256, DOUT = 128;
    const int N = in_sizes[0] / DIN;        // 40000
    const int E = in_sizes[1] / 2;          // 400000

    const float* x   = (const float*)d_in[0];
    const int*   ei  = (const int*)d_in[1];
    const float* W1  = (const float*)d_in[3];
    const float* as1 = (const float*)d_in[4];
    const float* ad1 = (const float*)d_in[5];
    const float* b1  = (const float*)d_in[6];
    const float* W2  = (const float*)d_in[7];
    const float* as2 = (const float*)d_in[8];
    const float* ad2 = (const float*)d_in[9];
    const float* b2  = (const float*)d_in[10];
    const float* W3  = (const float*)d_in[11];
    const float* as3 = (const float*)d_in[12];
    const float* ad3 = (const float*)d_in[13];
    const float* b3  = (const float*)d_in[14];
    float* outp = (float*)d_out;

    // workspace carve
    char* ws = (char*)d_ws;
    size_t off = 0;
    auto carve = [&](size_t bytes) { char* p = ws + off; off = (off + bytes + 255) & ~(size_t)255; return p; };
    unsigned short* hbuf = (unsigned short*)carve((size_t)N * DH * 2);  // 20 MB bf16
    unsigned short* gbuf = (unsigned short*)carve((size_t)N * DH * 2);  // 20 MB bf16
    float* als  = (float*)carve((size_t)N * 4);
    float* ald  = (float*)carve((size_t)N * 4);
    unsigned short* wt = (unsigned short*)carve((size_t)DH * DH * 2);
    int* cnt    = (int*)carve((size_t)N * 4);
    int* begptr = (int*)carve((size_t)N * 4);
    int* fill   = (int*)carve((size_t)N * 4);
    int* cursor = (int*)carve(256);
    int* colidx = (int*)carve((size_t)(E + N) * 4);
    (void)ws_size; (void)n_in; (void)out_size;

    const int* e_src = ei;
    const int* e_dst = ei + E;

    // CSR build (identical every call; segment order unimportant)
    k_init_cnt<<<(N + 255) / 256, 256, 0, stream>>>(cnt, cursor, N);
    k_hist<<<(E + 255) / 256, 256, 0, stream>>>(e_dst, cnt, E);
    k_assign<<<(N + 255) / 256, 256, 0, stream>>>(cnt, begptr, colidx, fill, cursor, N);
    k_scatter<<<(E + 255) / 256, 256, 0, stream>>>(e_src, e_dst, begptr, fill, colidx, E);

    const int nblk4 = (N + 3) / 4;
    const int mblk  = N / 64;

    // ---- layer 1: x[N,128] @ W1[128,256] ----
    k_transpose<<<(DIN * DH + 255) / 256, 256, 0, stream>>>(W1, wt, DIN, DH);
    k_gemm<256, float><<<mblk, 256, 0, stream>>>(x, wt, hbuf, as1, ad1, als, ald, DIN);
    k_edge<256, true, unsigned short><<<nblk4, 256, 0, stream>>>(hbuf, als, ald, begptr, cnt, colidx, b1, gbuf, N);

    // ---- layer 2: g[N,256] @ W2[256,256] ----
    k_transpose<<<(DH * DH + 255) / 256, 256, 0, stream>>>(W2, wt, DH, DH);
    k_gemm<256, unsigned short><<<mblk, 256, 0, stream>>>(gbuf, wt, hbuf, as2, ad2, als, ald, DH);
    k_edge<256, true, unsigned short><<<nblk4, 256, 0, stream>>>(hbuf, als, ald, begptr, cnt, colidx, b2, gbuf, N);

    // ---- layer 3: g[N,256] @ W3[256,128] ----
    k_transpose<<<(DH * DOUT + 255) / 256, 256, 0, stream>>>(W3, wt, DH, DOUT);
    k_gemm<128, unsigned short><<<mblk, 256, 0, stream>>>(gbuf, wt, hbuf, as3, ad3, als, ald, DH);
    k_edge<128, false, float><<<nblk4, 256, 0, stream>>>(hbuf, als, ald, begptr, cnt, colidx, b3, outp, N);
}

// Round 6
// 302.513 us; speedup vs baseline: 1.5077x; 1.0237x over previous
//
#include <hip/hip_runtime.h>
#include <hip/hip_bf16.h>
#include <type_traits>

// ---------- types ----------
typedef __attribute__((ext_vector_type(8))) short short8;   // 8 bf16 (4 VGPRs) MFMA A/B frag
typedef __attribute__((ext_vector_type(4))) float f32x4;    // MFMA C/D frag / float4
typedef __attribute__((ext_vector_type(2))) float f32x2;
typedef __attribute__((ext_vector_type(8))) unsigned short u16x8;

static __device__ __forceinline__ unsigned short f2b(float f) {
    unsigned int v = __float_as_uint(f);
    unsigned int r = (v + 0x7FFFu + ((v >> 16) & 1u)) >> 16;   // RNE
    return (unsigned short)r;
}
static __device__ __forceinline__ float b2f(unsigned short u) {
    return __uint_as_float(((unsigned int)u) << 16);
}

// ---------- CSR build (unordered segment allocation — no prefix scan) ----------
__global__ void k_init_cnt(int* cnt, int* cursor, int n) {
    int i = blockIdx.x * 256 + threadIdx.x;
    if (i < n) cnt[i] = 1;  // self-loop
    if (i == 0) *cursor = 0;
}

__global__ void k_hist(const int* __restrict__ dst, int* __restrict__ cnt, int E) {
    int e = blockIdx.x * 256 + threadIdx.x;
    if (e < E) atomicAdd(&cnt[dst[e]], 1);
}

// per-node segment allocation: wave-scan of cnt + one atomicAdd per wave.
// Also places the self-loop and inits fill=1.
__global__ void k_assign(const int* __restrict__ cnt, int* __restrict__ begptr,
                         int* __restrict__ colidx, int* __restrict__ fill,
                         int* __restrict__ cursor, int n) {
    int i = blockIdx.x * 256 + threadIdx.x;
    int lane = threadIdx.x & 63;
    int c = (i < n) ? cnt[i] : 0;
    int s = c;  // inclusive wave scan
#pragma unroll
    for (int off = 1; off < 64; off <<= 1) {
        int v = __shfl_up(s, off);
        if (lane >= off) s += v;
    }
    int wavesum = __shfl(s, 63);
    int base = 0;
    if (lane == 63) base = atomicAdd(cursor, wavesum);
    base = __shfl(base, 63);
    int beg = base + s - c;
    if (i < n) { begptr[i] = beg; colidx[beg] = i; fill[i] = 1; }
}

__global__ void k_scatter(const int* __restrict__ src, const int* __restrict__ dst,
                          const int* __restrict__ begptr, int* __restrict__ fill,
                          int* __restrict__ colidx, int E) {
    int e = blockIdx.x * 256 + threadIdx.x;
    if (e < E) {
        int s = src[e], d = dst[e];
        int pos = atomicAdd(&fill[d], 1);
        colidx[begptr[d] + pos] = s;
    }
}

// ---------- W transpose + cast (fp32 -> bf16): wt[n*K+k] = bf16(w[k*Nc+n]) ----------
__global__ void k_transpose(const float* __restrict__ w, unsigned short* __restrict__ wt,
                            int K, int Nc) {
    int i = blockIdx.x * 256 + threadIdx.x;
    if (i < K * Nc) {
        int k = i / Nc, n = i % Nc;
        wt[n * K + k] = f2b(w[i]);
    }
}

// ---------- MFMA GEMM + fused attention logits ----------
// H[M,NC] (bf16) = A[M,K] * B[K,NC];  als/ald[row] = H[row,:] . asrc/adst (fp32 acc)
// A is fp32 (layer 1 input) or bf16 (edge-layer outputs). B given transposed bf16 Bt[NC,K].
// block = 256 threads = 4 waves; tile 64(M) x NC(full); BK = 32
template<int NC, typename AT>
__global__ __launch_bounds__(256) void k_gemm(const AT* __restrict__ A,
                                              const unsigned short* __restrict__ Bt,
                                              unsigned short* __restrict__ H,
                                              const float* __restrict__ asrc,
                                              const float* __restrict__ adst,
                                              float* __restrict__ als,
                                              float* __restrict__ ald,
                                              int K) {
    __shared__ unsigned short As[64][40];   // 32 cols + pad
    __shared__ unsigned short Bs[NC][40];
    const int tid  = threadIdx.x;
    const int lane = tid & 63;
    const int wv   = tid >> 6;
    const int rowBase = blockIdx.x * 64;
    const int quad = lane >> 4;
    const int l16  = lane & 15;
    constexpr int NT = NC / 16;
    f32x4 acc[NT] = {};

    const int ar = tid >> 2;            // A staging row 0..63
    const int ak = (tid & 3) * 8;       // A staging k-chunk

    for (int kk = 0; kk < K; kk += 32) {
        // stage A
        if constexpr (std::is_same_v<AT, float>) {
            const float* ap = A + (size_t)(rowBase + ar) * K + kk + ak;
            f32x4 a0 = *(const f32x4*)ap;
            f32x4 a1 = *(const f32x4*)(ap + 4);
            short8 s;
#pragma unroll
            for (int v = 0; v < 4; v++) { s[v] = (short)f2b(a0[v]); s[4 + v] = (short)f2b(a1[v]); }
            *(short8*)&As[ar][ak] = s;
        } else {
            *(short8*)&As[ar][ak] = *(const short8*)(A + (size_t)(rowBase + ar) * K + kk + ak);
        }
        // stage B
#pragma unroll
        for (int c = tid; c < NC * 4; c += 256) {
            int br = c >> 2, bk = (c & 3) * 8;
            *(short8*)&Bs[br][bk] = *(const short8*)(Bt + (size_t)br * K + kk + bk);
        }
        __syncthreads();
        short8 af = *(const short8*)&As[wv * 16 + l16][quad * 8];
#pragma unroll
        for (int nt = 0; nt < NT; nt++) {
            short8 bf = *(const short8*)&Bs[nt * 16 + l16][quad * 8];
            acc[nt] = __builtin_amdgcn_mfma_f32_16x16x32_bf16(af, bf, acc[nt], 0, 0, 0);
        }
        __syncthreads();
    }

    // epilogue: store bf16 H + fused als/ald
    float avs[NT], avd[NT];
#pragma unroll
    for (int nt = 0; nt < NT; nt++) {
        int gcol = nt * 16 + l16;
        avs[nt] = asrc[gcol];
        avd[nt] = adst[gcol];
#pragma unroll
        for (int r = 0; r < 4; r++) {
            int grow = rowBase + wv * 16 + quad * 4 + r;
            H[(size_t)grow * NC + gcol] = f2b(acc[nt][r]);
        }
    }
#pragma unroll
    for (int r = 0; r < 4; r++) {
        float ps = 0.f, pd = 0.f;
#pragma unroll
        for (int nt = 0; nt < NT; nt++) { ps += acc[nt][r] * avs[nt]; pd += acc[nt][r] * avd[nt]; }
#pragma unroll
        for (int off = 8; off; off >>= 1) { ps += __shfl_xor(ps, off); pd += __shfl_xor(pd, off); }
        if (l16 == 0) {
            int grow = rowBase + wv * 16 + quad * 4 + r;
            als[grow] = ps;
            ald[grow] = pd;
        }
    }
}

// ---------- edge softmax + weighted aggregation, one wave per dst node ----------
// Pass 3 processes FOUR edges per iteration: 16-lane quarter q takes edge 4t+q.
// Each lane covers DOUT/16 dims (32B @ DH=256, 16B @ DOUT=128). h bf16; fp32 accumulate.
template<int DOUT, bool RELU, typename OutT>
__global__ __launch_bounds__(256) void k_edge(const unsigned short* __restrict__ h,
                                              const float* __restrict__ als,
                                              const float* __restrict__ ald,
                                              const int* __restrict__ begptr,
                                              const int* __restrict__ cnt,
                                              const int* __restrict__ colidx,
                                              const float* __restrict__ bias,
                                              OutT* __restrict__ out, int N) {
    int node = blockIdx.x * 4 + (threadIdx.x >> 6);
    if (node >= N) return;
    int lane = threadIdx.x & 63;
    int beg = begptr[node];
    int deg = cnt[node];
    float aldi = ald[node];

    // pass 1: max; lanes j<64 cache their edge
    float m = -1e30f;
    float e_lane = -1e30f;
    int   s_lane = 0;
    for (int j = lane; j < deg; j += 64) {
        int s = colidx[beg + j];
        float e = als[s] + aldi;
        e = e > 0.f ? e : 0.2f * e;
        if (j < 64) { e_lane = e; s_lane = s; }
        m = fmaxf(m, e);
    }
#pragma unroll
    for (int off = 32; off; off >>= 1) m = fmaxf(m, __shfl_xor(m, off));

    // pass 2: denom
    float dsum = (lane < deg) ? __expf(e_lane - m) : 0.f;
    for (int j = lane + 64; j < deg; j += 64) {
        int s = colidx[beg + j];
        float e = als[s] + aldi;
        e = e > 0.f ? e : 0.2f * e;
        dsum += __expf(e - m);
    }
#pragma unroll
    for (int off = 32; off; off >>= 1) dsum += __shfl_xor(dsum, off);
    float inv = 1.0f / dsum;
    float w_lane = (lane < deg) ? __expf(e_lane - m) * inv : 0.f;   // lanes >= deg carry 0

    // pass 3: quad-edge weighted gather-accumulate (16-lane row quarters)
    constexpr int QV  = DOUT / 16;         // dims per lane (16 @ 256, 8 @ 128)
    constexpr int NC8 = QV / 8;            // u16x8 chunks per lane (2 or 1)
    const int l16g    = lane & 15;
    const int quarter = lane >> 4;
    const size_t dimOff = (size_t)l16g * QV;
    float acc[QV] = {};
    int lim = deg < 64 ? deg : 64;
    for (int t = 0; 4 * t < lim; t++) {
        int idx = 4 * t + quarter;         // idx >= deg -> wj == 0, load is safe (s_lane=0)
        float wj = __shfl(w_lane, idx);
        int   sj = __shfl(s_lane, idx);
        const unsigned short* hp = h + (size_t)sj * DOUT + dimOff;
        u16x8 c[NC8];
#pragma unroll
        for (int u = 0; u < NC8; u++) c[u] = *(const u16x8*)(hp + 8 * u);
#pragma unroll
        for (int u = 0; u < NC8; u++)
#pragma unroll
            for (int v = 0; v < 8; v++) acc[8 * u + v] += wj * b2f(c[u][v]);
    }
    for (int j = 64; j < deg; j++) {       // rare overflow path (deg>64): quarter 0 only
        int sj = colidx[beg + j];
        float e = als[sj] + aldi;
        e = e > 0.f ? e : 0.2f * e;
        float wj = __expf(e - m) * inv;
        if (quarter == 0) {
            const unsigned short* hp = h + (size_t)sj * DOUT + dimOff;
#pragma unroll
            for (int u = 0; u < NC8; u++) {
                u16x8 c = *(const u16x8*)(hp + 8 * u);
#pragma unroll
                for (int v = 0; v < 8; v++) acc[8 * u + v] += wj * b2f(c[v]);
            }
        }
    }
    // combine quarters: xor 16 then xor 32 -> every lane holds the full sum
#pragma unroll
    for (int v = 0; v < QV; v++) {
        acc[v] += __shfl_xor(acc[v], 16);
        acc[v] += __shfl_xor(acc[v], 32);
    }

    if (quarter == 0) {
        if constexpr (std::is_same_v<OutT, float>) {
            float* op = out + (size_t)node * DOUT + dimOff;
#pragma unroll
            for (int u = 0; u < QV / 4; u++) {
                f32x4 bv = *(const f32x4*)(bias + dimOff + 4 * u);
                f32x4 ov;
#pragma unroll
                for (int v = 0; v < 4; v++) {
                    float val = acc[4 * u + v] + bv[v];
                    if (RELU) val = fmaxf(val, 0.f);
                    ov[v] = val;
                }
                *(f32x4*)(op + 4 * u) = ov;
            }
        } else {
            unsigned short* op = out + (size_t)node * DOUT + dimOff;
#pragma unroll
            for (int u = 0; u < NC8; u++) {
                u16x8 ov;
#pragma unroll
                for (int v = 0; v < 8; v++) {
                    float val = acc[8 * u + v] + bias[dimOff + 8 * u + v];
                    if (RELU) val = fmaxf(val, 0.f);
                    ov[v] = f2b(val);
                }
                *(u16x8*)(op + 8 * u) = ov;
            }
        }
    }
}

// ---------- launch ----------
extern "C" void kernel_launch(void* const* d_in, const int* in_sizes, int n_in,
                              void* d_out, int out_size, void* d_ws, size_t ws_size,
                              hipStream_t stream) {
    const int DIN = 128, DH = 256, DOUT = 128;
    const int N = in_sizes[0] / DIN;        // 40000
    const int E = in_sizes[1] / 2;          // 400000

    const float* x   = (const float*)d_in[0];
    const int*   ei  = (const int*)d_in[1];
    const float* W1  = (const float*)d_in[3];
    const float* as1 = (const float*)d_in[4];
    const float* ad1 = (const float*)d_in[5];
    const float* b1  = (const float*)d_in[6];
    const float* W2  = (const float*)d_in[7];
    const float* as2 = (const float*)d_in[8];
    const float* ad2 = (const float*)d_in[9];
    const float* b2  = (const float*)d_in[10];
    const float* W3  = (const float*)d_in[11];
    const float* as3 = (const float*)d_in[12];
    const float* ad3 = (const float*)d_in[13];
    const float* b3  = (const float*)d_in[14];
    float* outp = (float*)d_out;

    // workspace carve
    char* ws = (char*)d_ws;
    size_t off = 0;
    auto carve = [&](size_t bytes) { char* p = ws + off; off = (off + bytes + 255) & ~(size_t)255; return p; };
    unsigned short* hbuf = (unsigned short*)carve((size_t)N * DH * 2);  // 20 MB bf16
    unsigned short* gbuf = (unsigned short*)carve((size_t)N * DH * 2);  // 20 MB bf16
    float* als  = (float*)carve((size_t)N * 4);
    float* ald  = (float*)carve((size_t)N * 4);
    unsigned short* wt = (unsigned short*)carve((size_t)DH * DH * 2);
    int* cnt    = (int*)carve((size_t)N * 4);
    int* begptr = (int*)carve((size_t)N * 4);
    int* fill   = (int*)carve((size_t)N * 4);
    int* cursor = (int*)carve(256);
    int* colidx = (int*)carve((size_t)(E + N) * 4);
    (void)ws_size; (void)n_in; (void)out_size;

    const int* e_src = ei;
    const int* e_dst = ei + E;

    // CSR build (identical every call; segment order unimportant)
    k_init_cnt<<<(N + 255) / 256, 256, 0, stream>>>(cnt, cursor, N);
    k_hist<<<(E + 255) / 256, 256, 0, stream>>>(e_dst, cnt, E);
    k_assign<<<(N + 255) / 256, 256, 0, stream>>>(cnt, begptr, colidx, fill, cursor, N);
    k_scatter<<<(E + 255) / 256, 256, 0, stream>>>(e_src, e_dst, begptr, fill, colidx, E);

    const int nblk4 = (N + 3) / 4;
    const int mblk  = N / 64;

    // ---- layer 1: x[N,128] @ W1[128,256] ----
    k_transpose<<<(DIN * DH + 255) / 256, 256, 0, stream>>>(W1, wt, DIN, DH);
    k_gemm<256, float><<<mblk, 256, 0, stream>>>(x, wt, hbuf, as1, ad1, als, ald, DIN);
    k_edge<256, true, unsigned short><<<nblk4, 256, 0, stream>>>(hbuf, als, ald, begptr, cnt, colidx, b1, gbuf, N);

    // ---- layer 2: g[N,256] @ W2[256,256] ----
    k_transpose<<<(DH * DH + 255) / 256, 256, 0, stream>>>(W2, wt, DH, DH);
    k_gemm<256, unsigned short><<<mblk, 256, 0, stream>>>(gbuf, wt, hbuf, as2, ad2, als, ald, DH);
    k_edge<256, true, unsigned short><<<nblk4, 256, 0, stream>>>(hbuf, als, ald, begptr, cnt, colidx, b2, gbuf, N);

    // ---- layer 3: g[N,256] @ W3[256,128] ----
    k_transpose<<<(DH * DOUT + 255) / 256, 256, 0, stream>>>(W3, wt, DH, DOUT);
    k_gemm<128, unsigned short><<<mblk, 256, 0, stream>>>(gbuf, wt, hbuf, as3, ad3, als, ald, DH);
    k_edge<128, false, float><<<nblk4, 256, 0, stream>>>(hbuf, als, ald, begptr, cnt, colidx, b3, outp, N);
}

// Round 7
// 301.891 us; speedup vs baseline: 1.5108x; 1.0021x over previous
//
#include <hip/hip_runtime.h>
#include <hip/hip_bf16.h>
#include <type_traits>

// ---------- types ----------
typedef __attribute__((ext_vector_type(8))) short short8;   // 8 bf16 (4 VGPRs) MFMA A/B frag
typedef __attribute__((ext_vector_type(4))) float f32x4;    // MFMA C/D frag / float4
typedef __attribute__((ext_vector_type(8))) unsigned short u16x8;

static __device__ __forceinline__ unsigned short f2b(float f) {
    unsigned int v = __float_as_uint(f);
    unsigned int r = (v + 0x7FFFu + ((v >> 16) & 1u)) >> 16;   // RNE
    return (unsigned short)r;
}
static __device__ __forceinline__ float b2f(unsigned short u) {
    return __uint_as_float(((unsigned int)u) << 16);
}

// ---------- CSR build (unordered segment allocation — no prefix scan) ----------
// cnt[] counts REAL edges only (self-loop added as +1 downstream). cnt/cursor zeroed by memsetAsync.
__global__ void k_hist(const int* __restrict__ dst, int* __restrict__ cnt, int E) {
    int e = blockIdx.x * 256 + threadIdx.x;
    if (e < E) atomicAdd(&cnt[dst[e]], 1);
}

// per-node segment allocation: wave-scan of (cnt+1) + one atomicAdd per wave.
// Places the self-loop at slot 0 and inits fill=1.
__global__ void k_assign(const int* __restrict__ cnt, int* __restrict__ begptr,
                         int* __restrict__ colidx, int* __restrict__ fill,
                         int* __restrict__ cursor, int n) {
    int i = blockIdx.x * 256 + threadIdx.x;
    int lane = threadIdx.x & 63;
    int c = (i < n) ? cnt[i] + 1 : 0;
    int s = c;  // inclusive wave scan
#pragma unroll
    for (int off = 1; off < 64; off <<= 1) {
        int v = __shfl_up(s, off);
        if (lane >= off) s += v;
    }
    int wavesum = __shfl(s, 63);
    int base = 0;
    if (lane == 63) base = atomicAdd(cursor, wavesum);
    base = __shfl(base, 63);
    int beg = base + s - c;
    if (i < n) { begptr[i] = beg; colidx[beg] = i; fill[i] = 1; }
}

__global__ void k_scatter(const int* __restrict__ src, const int* __restrict__ dst,
                          const int* __restrict__ begptr, int* __restrict__ fill,
                          int* __restrict__ colidx, int E) {
    int e = blockIdx.x * 256 + threadIdx.x;
    if (e < E) {
        int s = src[e], d = dst[e];
        int pos = atomicAdd(&fill[d], 1);
        colidx[begptr[d] + pos] = s;
    }
}

// ---------- all-weights transpose + cast (fp32 -> bf16): t[n*K+k] = bf16(w[k*Nc+n]) ----------
__global__ void k_transpose3(const float* __restrict__ w1, unsigned short* __restrict__ t1,
                             const float* __restrict__ w2, unsigned short* __restrict__ t2,
                             const float* __restrict__ w3, unsigned short* __restrict__ t3,
                             int K1, int N1, int K2, int N2, int K3, int N3) {
    int i = blockIdx.x * 256 + threadIdx.x;
    int n1 = K1 * N1, n2 = K2 * N2, n3 = K3 * N3;
    if (i < n1) {
        int k = i / N1, n = i % N1;
        t1[n * K1 + k] = f2b(w1[i]);
    } else if (i < n1 + n2) {
        int j = i - n1, k = j / N2, n = j % N2;
        t2[n * K2 + k] = f2b(w2[j]);
    } else if (i < n1 + n2 + n3) {
        int j = i - n1 - n2, k = j / N3, n = j % N3;
        t3[n * K3 + k] = f2b(w3[j]);
    }
}

// ---------- MFMA GEMM + fused attention logits ----------
// H[M,NC] (bf16) = A[M,K] * B[K,NC];  als/ald[row] = H[row,:] . asrc/adst (fp32 acc)
// 4 waves tiled 2x2 over the 64xNC block: each wave 32 rows x NC/2 cols.
// Per k-iter per wave: 2 A-frag + NC/32 B-frag ds_reads for 2*(NC/32) MFMA.
template<int NC, typename AT>
__global__ __launch_bounds__(256) void k_gemm(const AT* __restrict__ A,
                                              const unsigned short* __restrict__ Bt,
                                              unsigned short* __restrict__ H,
                                              const float* __restrict__ asrc,
                                              const float* __restrict__ adst,
                                              float* __restrict__ als,
                                              float* __restrict__ ald,
                                              int K) {
    __shared__ unsigned short As[64][40];   // 32 cols + pad
    __shared__ unsigned short Bs[NC][40];
    __shared__ float sps[64], spd[64];
    const int tid  = threadIdx.x;
    const int lane = tid & 63;
    const int wv   = tid >> 6;
    const int rowBase = blockIdx.x * 64;
    const int quad = lane >> 4;
    const int l16  = lane & 15;
    constexpr int CG = NC / 32;         // col-frags per wave (8 @ NC=256, 4 @ NC=128)
    const int wrow = (wv & 1) * 32;     // wave row offset within tile
    const int wcol = (wv >> 1) * (NC / 2);  // wave col offset
    f32x4 acc[2][CG] = {};

    if (tid < 64) { sps[tid] = 0.f; spd[tid] = 0.f; }

    const int ar = tid >> 2;            // A staging row 0..63
    const int ak = (tid & 3) * 8;       // A staging k-chunk

    for (int kk = 0; kk < K; kk += 32) {
        // stage A
        if constexpr (std::is_same_v<AT, float>) {
            const float* ap = A + (size_t)(rowBase + ar) * K + kk + ak;
            f32x4 a0 = *(const f32x4*)ap;
            f32x4 a1 = *(const f32x4*)(ap + 4);
            short8 s;
#pragma unroll
            for (int v = 0; v < 4; v++) { s[v] = (short)f2b(a0[v]); s[4 + v] = (short)f2b(a1[v]); }
            *(short8*)&As[ar][ak] = s;
        } else {
            *(short8*)&As[ar][ak] = *(const short8*)(A + (size_t)(rowBase + ar) * K + kk + ak);
        }
        // stage B
#pragma unroll
        for (int c = tid; c < NC * 4; c += 256) {
            int br = c >> 2, bk = (c & 3) * 8;
            *(short8*)&Bs[br][bk] = *(const short8*)(Bt + (size_t)br * K + kk + bk);
        }
        __syncthreads();
        short8 af0 = *(const short8*)&As[wrow + l16][quad * 8];
        short8 af1 = *(const short8*)&As[wrow + 16 + l16][quad * 8];
#pragma unroll
        for (int cg = 0; cg < CG; cg++) {
            short8 bf = *(const short8*)&Bs[wcol + cg * 16 + l16][quad * 8];
            acc[0][cg] = __builtin_amdgcn_mfma_f32_16x16x32_bf16(af0, bf, acc[0][cg], 0, 0, 0);
            acc[1][cg] = __builtin_amdgcn_mfma_f32_16x16x32_bf16(af1, bf, acc[1][cg], 0, 0, 0);
        }
        __syncthreads();
    }

    // epilogue: store bf16 H + fused partial logits
    float avs[CG], avd[CG];
#pragma unroll
    for (int cg = 0; cg < CG; cg++) {
        int gcol = wcol + cg * 16 + l16;
        avs[cg] = asrc[gcol];
        avd[cg] = adst[gcol];
#pragma unroll
        for (int rg = 0; rg < 2; rg++)
#pragma unroll
            for (int r = 0; r < 4; r++) {
                int grow = rowBase + wrow + rg * 16 + quad * 4 + r;
                H[(size_t)grow * NC + gcol] = f2b(acc[rg][cg][r]);
            }
    }
#pragma unroll
    for (int rg = 0; rg < 2; rg++)
#pragma unroll
        for (int r = 0; r < 4; r++) {
            float ps = 0.f, pd = 0.f;
#pragma unroll
            for (int cg = 0; cg < CG; cg++) { ps += acc[rg][cg][r] * avs[cg]; pd += acc[rg][cg][r] * avd[cg]; }
#pragma unroll
            for (int off = 8; off; off >>= 1) { ps += __shfl_xor(ps, off); pd += __shfl_xor(pd, off); }
            if (l16 == 0) {
                int lrow = wrow + rg * 16 + quad * 4 + r;
                atomicAdd(&sps[lrow], ps);
                atomicAdd(&spd[lrow], pd);
            }
        }
    __syncthreads();
    if (tid < 64) { als[rowBase + tid] = sps[tid]; ald[rowBase + tid] = spd[tid]; }
}

// ---------- edge softmax + weighted aggregation, one wave per dst node ----------
// Pass 3 processes FOUR edges per iteration: 16-lane quarter q takes edge 4t+q.
// Each lane covers DOUT/16 dims (32B @ DH=256, 16B @ DOUT=128). h bf16; fp32 accumulate.
template<int DOUT, bool RELU, typename OutT>
__global__ __launch_bounds__(256) void k_edge(const unsigned short* __restrict__ h,
                                              const float* __restrict__ als,
                                              const float* __restrict__ ald,
                                              const int* __restrict__ begptr,
                                              const int* __restrict__ cnt,
                                              const int* __restrict__ colidx,
                                              const float* __restrict__ bias,
                                              OutT* __restrict__ out, int N) {
    int node = blockIdx.x * 4 + (threadIdx.x >> 6);
    if (node >= N) return;
    int lane = threadIdx.x & 63;
    int beg = begptr[node];
    int deg = cnt[node] + 1;   // + self-loop

    float aldi = ald[node];

    // pass 1: max; lanes j<64 cache their edge
    float m = -1e30f;
    float e_lane = -1e30f;
    int   s_lane = 0;
    for (int j = lane; j < deg; j += 64) {
        int s = colidx[beg + j];
        float e = als[s] + aldi;
        e = e > 0.f ? e : 0.2f * e;
        if (j < 64) { e_lane = e; s_lane = s; }
        m = fmaxf(m, e);
    }
#pragma unroll
    for (int off = 32; off; off >>= 1) m = fmaxf(m, __shfl_xor(m, off));

    // pass 2: denom
    float dsum = (lane < deg) ? __expf(e_lane - m) : 0.f;
    for (int j = lane + 64; j < deg; j += 64) {
        int s = colidx[beg + j];
        float e = als[s] + aldi;
        e = e > 0.f ? e : 0.2f * e;
        dsum += __expf(e - m);
    }
#pragma unroll
    for (int off = 32; off; off >>= 1) dsum += __shfl_xor(dsum, off);
    float inv = 1.0f / dsum;
    float w_lane = (lane < deg) ? __expf(e_lane - m) * inv : 0.f;   // lanes >= deg carry 0

    // pass 3: quad-edge weighted gather-accumulate (16-lane row quarters)
    constexpr int QV  = DOUT / 16;         // dims per lane (16 @ 256, 8 @ 128)
    constexpr int NC8 = QV / 8;            // u16x8 chunks per lane (2 or 1)
    const int l16g    = lane & 15;
    const int quarter = lane >> 4;
    const size_t dimOff = (size_t)l16g * QV;
    float acc[QV] = {};
    int lim = deg < 64 ? deg : 64;
    for (int t = 0; 4 * t < lim; t++) {
        int idx = 4 * t + quarter;         // idx >= deg -> wj == 0, load is safe (s_lane=0)
        float wj = __shfl(w_lane, idx);
        int   sj = __shfl(s_lane, idx);
        const unsigned short* hp = h + (size_t)sj * DOUT + dimOff;
        u16x8 c[NC8];
#pragma unroll
        for (int u = 0; u < NC8; u++) c[u] = *(const u16x8*)(hp + 8 * u);
#pragma unroll
        for (int u = 0; u < NC8; u++)
#pragma unroll
            for (int v = 0; v < 8; v++) acc[8 * u + v] += wj * b2f(c[u][v]);
    }
    for (int j = 64; j < deg; j++) {       // rare overflow path (deg>64): quarter 0 only
        int sj = colidx[beg + j];
        float e = als[sj] + aldi;
        e = e > 0.f ? e : 0.2f * e;
        float wj = __expf(e - m) * inv;
        if (quarter == 0) {
            const unsigned short* hp = h + (size_t)sj * DOUT + dimOff;
#pragma unroll
            for (int u = 0; u < NC8; u++) {
                u16x8 c = *(const u16x8*)(hp + 8 * u);
#pragma unroll
                for (int v = 0; v < 8; v++) acc[8 * u + v] += wj * b2f(c[v]);
            }
        }
    }
    // combine quarters: xor 16 then xor 32 -> every lane holds the full sum
#pragma unroll
    for (int v = 0; v < QV; v++) {
        acc[v] += __shfl_xor(acc[v], 16);
        acc[v] += __shfl_xor(acc[v], 32);
    }

    if (quarter == 0) {
        if constexpr (std::is_same_v<OutT, float>) {
            float* op = out + (size_t)node * DOUT + dimOff;
#pragma unroll
            for (int u = 0; u < QV / 4; u++) {
                f32x4 bv = *(const f32x4*)(bias + dimOff + 4 * u);
                f32x4 ov;
#pragma unroll
                for (int v = 0; v < 4; v++) {
                    float val = acc[4 * u + v] + bv[v];
                    if (RELU) val = fmaxf(val, 0.f);
                    ov[v] = val;
                }
                *(f32x4*)(op + 4 * u) = ov;
            }
        } else {
            unsigned short* op = out + (size_t)node * DOUT + dimOff;
#pragma unroll
            for (int u = 0; u < NC8; u++) {
                u16x8 ov;
#pragma unroll
                for (int v = 0; v < 8; v++) {
                    float val = acc[8 * u + v] + bias[dimOff + 8 * u + v];
                    if (RELU) val = fmaxf(val, 0.f);
                    ov[v] = f2b(val);
                }
                *(u16x8*)(op + 8 * u) = ov;
            }
        }
    }
}

// ---------- launch ----------
extern "C" void kernel_launch(void* const* d_in, const int* in_sizes, int n_in,
                              void* d_out, int out_size, void* d_ws, size_t ws_size,
                              hipStream_t stream) {
    const int DIN = 128, DH = 256, DOUT = 128;
    const int N = in_sizes[0] / DIN;        // 40000
    const int E = in_sizes[1] / 2;          // 400000

    const float* x   = (const float*)d_in[0];
    const int*   ei  = (const int*)d_in[1];
    const float* W1  = (const float*)d_in[3];
    const float* as1 = (const float*)d_in[4];
    const float* ad1 = (const float*)d_in[5];
    const float* b1  = (const float*)d_in[6];
    const float* W2  = (const float*)d_in[7];
    const float* as2 = (const float*)d_in[8];
    const float* ad2 = (const float*)d_in[9];
    const float* b2  = (const float*)d_in[10];
    const float* W3  = (const float*)d_in[11];
    const float* as3 = (const float*)d_in[12];
    const float* ad3 = (const float*)d_in[13];
    const float* b3  = (const float*)d_in[14];
    float* outp = (float*)d_out;

    // workspace carve
    char* ws = (char*)d_ws;
    size_t off = 0;
    auto carve = [&](size_t bytes) { char* p = ws + off; off = (off + bytes + 255) & ~(size_t)255; return p; };
    unsigned short* hbuf = (unsigned short*)carve((size_t)N * DH * 2);  // 20 MB bf16
    unsigned short* gbuf = (unsigned short*)carve((size_t)N * DH * 2);  // 20 MB bf16
    float* als  = (float*)carve((size_t)N * 4);
    float* ald  = (float*)carve((size_t)N * 4);
    unsigned short* wt1 = (unsigned short*)carve((size_t)DIN * DH * 2);
    unsigned short* wt2 = (unsigned short*)carve((size_t)DH * DH * 2);
    unsigned short* wt3 = (unsigned short*)carve((size_t)DH * DOUT * 2);
    int* cnt    = (int*)carve((size_t)N * 4);
    int* cursor = (int*)carve(256);
    int* begptr = (int*)carve((size_t)N * 4);
    int* fill   = (int*)carve((size_t)N * 4);
    int* colidx = (int*)carve((size_t)(E + N) * 4);
    (void)ws_size; (void)n_in; (void)out_size;

    const int* e_src = ei;
    const int* e_dst = ei + E;

    // zero cnt..cursor in one async memset (allowed under graph capture)
    hipMemsetAsync(cnt, 0, (size_t)((char*)cursor - (char*)cnt) + 4, stream);

    // all-weight transpose up front
    {
        int tot = DIN * DH + DH * DH + DH * DOUT;
        k_transpose3<<<(tot + 255) / 256, 256, 0, stream>>>(W1, wt1, W2, wt2, W3, wt3,
                                                            DIN, DH, DH, DH, DH, DOUT);
    }

    // CSR build (identical every call; segment order unimportant)
    k_hist<<<(E + 255) / 256, 256, 0, stream>>>(e_dst, cnt, E);
    k_assign<<<(N + 255) / 256, 256, 0, stream>>>(cnt, begptr, colidx, fill, cursor, N);
    k_scatter<<<(E + 255) / 256, 256, 0, stream>>>(e_src, e_dst, begptr, fill, colidx, E);

    const int nblk4 = (N + 3) / 4;
    const int mblk  = N / 64;

    // ---- layer 1: x[N,128] @ W1[128,256] ----
    k_gemm<256, float><<<mblk, 256, 0, stream>>>(x, wt1, hbuf, as1, ad1, als, ald, DIN);
    k_edge<256, true, unsigned short><<<nblk4, 256, 0, stream>>>(hbuf, als, ald, begptr, cnt, colidx, b1, gbuf, N);

    // ---- layer 2: g[N,256] @ W2[256,256] ----
    k_gemm<256, unsigned short><<<mblk, 256, 0, stream>>>(gbuf, wt2, hbuf, as2, ad2, als, ald, DH);
    k_edge<256, true, unsigned short><<<nblk4, 256, 0, stream>>>(hbuf, als, ald, begptr, cnt, colidx, b2, gbuf, N);

    // ---- layer 3: g[N,256] @ W3[256,128] ----
    k_gemm<128, unsigned short><<<mblk, 256, 0, stream>>>(gbuf, wt3, hbuf, as3, ad3, als, ald, DH);
    k_edge<128, false, float><<<nblk4, 256, 0, stream>>>(hbuf, als, ald, begptr, cnt, colidx, b3, outp, N);
}

// Round 8
// 301.577 us; speedup vs baseline: 1.5123x; 1.0010x over previous
//
#include <hip/hip_runtime.h>
#include <hip/hip_bf16.h>
#include <type_traits>

// ---------- types ----------
typedef __attribute__((ext_vector_type(8))) short short8;   // 8 bf16 (4 VGPRs) MFMA A/B frag
typedef __attribute__((ext_vector_type(4))) float f32x4;    // MFMA C/D frag / float4
typedef __attribute__((ext_vector_type(8))) unsigned short u16x8;

static __device__ __forceinline__ unsigned short f2b(float f) {
    unsigned int v = __float_as_uint(f);
    unsigned int r = (v + 0x7FFFu + ((v >> 16) & 1u)) >> 16;   // RNE
    return (unsigned short)r;
}
static __device__ __forceinline__ float b2f(unsigned short u) {
    return __uint_as_float(((unsigned int)u) << 16);
}

// ---------- CSR build (unordered segment allocation — no prefix scan) ----------
// cnt[] counts REAL edges only (self-loop added as +1 downstream). cnt/cursor zeroed by memsetAsync.
__global__ void k_hist(const int* __restrict__ dst, int* __restrict__ cnt, int E) {
    int e = blockIdx.x * 256 + threadIdx.x;
    if (e < E) atomicAdd(&cnt[dst[e]], 1);
}

// per-node segment allocation: wave-scan of (cnt+1) + one atomicAdd per wave.
// Places the self-loop at slot 0; fill[i] holds the ABSOLUTE next write slot (beg+1).
__global__ void k_assign(const int* __restrict__ cnt, int* __restrict__ begptr,
                         int* __restrict__ colidx, int* __restrict__ fill,
                         int* __restrict__ cursor, int n) {
    int i = blockIdx.x * 256 + threadIdx.x;
    int lane = threadIdx.x & 63;
    int c = (i < n) ? cnt[i] + 1 : 0;
    int s = c;  // inclusive wave scan
#pragma unroll
    for (int off = 1; off < 64; off <<= 1) {
        int v = __shfl_up(s, off);
        if (lane >= off) s += v;
    }
    int wavesum = __shfl(s, 63);
    int base = 0;
    if (lane == 63) base = atomicAdd(cursor, wavesum);
    base = __shfl(base, 63);
    int beg = base + s - c;
    if (i < n) { begptr[i] = beg; colidx[beg] = i; fill[i] = beg + 1; }
}

// scatter: one atomic on fill[d] gives the absolute colidx slot — no begptr read.
__global__ void k_scatter(const int* __restrict__ src, const int* __restrict__ dst,
                          int* __restrict__ fill, int* __restrict__ colidx, int E) {
    int e = blockIdx.x * 256 + threadIdx.x;
    if (e < E) {
        int s = src[e], d = dst[e];
        int pos = atomicAdd(&fill[d], 1);
        colidx[pos] = s;
    }
}

// ---------- all-weights transpose + cast (fp32 -> bf16): t[n*K+k] = bf16(w[k*Nc+n]) ----------
__global__ void k_transpose3(const float* __restrict__ w1, unsigned short* __restrict__ t1,
                             const float* __restrict__ w2, unsigned short* __restrict__ t2,
                             const float* __restrict__ w3, unsigned short* __restrict__ t3,
                             int K1, int N1, int K2, int N2, int K3, int N3) {
    int i = blockIdx.x * 256 + threadIdx.x;
    int n1 = K1 * N1, n2 = K2 * N2, n3 = K3 * N3;
    if (i < n1) {
        int k = i / N1, n = i % N1;
        t1[n * K1 + k] = f2b(w1[i]);
    } else if (i < n1 + n2) {
        int j = i - n1, k = j / N2, n = j % N2;
        t2[n * K2 + k] = f2b(w2[j]);
    } else if (i < n1 + n2 + n3) {
        int j = i - n1 - n2, k = j / N3, n = j % N3;
        t3[n * K3 + k] = f2b(w3[j]);
    }
}

// ---------- MFMA GEMM + fused attention logits ----------
// H[M,NC] (bf16) = A[M,K] * B[K,NC];  als/ald[row] = H[row,:] . asrc/adst (fp32 acc)
// 4 waves tiled 2x2 over the 64xNC block: each wave 32 rows x NC/2 cols.
template<int NC, typename AT>
__global__ __launch_bounds__(256) void k_gemm(const AT* __restrict__ A,
                                              const unsigned short* __restrict__ Bt,
                                              unsigned short* __restrict__ H,
                                              const float* __restrict__ asrc,
                                              const float* __restrict__ adst,
                                              float* __restrict__ als,
                                              float* __restrict__ ald,
                                              int K) {
    __shared__ unsigned short As[64][40];   // 32 cols + pad
    __shared__ unsigned short Bs[NC][40];
    __shared__ float sps[64], spd[64];
    const int tid  = threadIdx.x;
    const int lane = tid & 63;
    const int wv   = tid >> 6;
    const int rowBase = blockIdx.x * 64;
    const int quad = lane >> 4;
    const int l16  = lane & 15;
    constexpr int CG = NC / 32;         // col-frags per wave (8 @ NC=256, 4 @ NC=128)
    const int wrow = (wv & 1) * 32;     // wave row offset within tile
    const int wcol = (wv >> 1) * (NC / 2);  // wave col offset
    f32x4 acc[2][CG] = {};

    if (tid < 64) { sps[tid] = 0.f; spd[tid] = 0.f; }

    const int ar = tid >> 2;            // A staging row 0..63
    const int ak = (tid & 3) * 8;       // A staging k-chunk

    for (int kk = 0; kk < K; kk += 32) {
        // stage A
        if constexpr (std::is_same_v<AT, float>) {
            const float* ap = A + (size_t)(rowBase + ar) * K + kk + ak;
            f32x4 a0 = *(const f32x4*)ap;
            f32x4 a1 = *(const f32x4*)(ap + 4);
            short8 s;
#pragma unroll
            for (int v = 0; v < 4; v++) { s[v] = (short)f2b(a0[v]); s[4 + v] = (short)f2b(a1[v]); }
            *(short8*)&As[ar][ak] = s;
        } else {
            *(short8*)&As[ar][ak] = *(const short8*)(A + (size_t)(rowBase + ar) * K + kk + ak);
        }
        // stage B
#pragma unroll
        for (int c = tid; c < NC * 4; c += 256) {
            int br = c >> 2, bk = (c & 3) * 8;
            *(short8*)&Bs[br][bk] = *(const short8*)(Bt + (size_t)br * K + kk + bk);
        }
        __syncthreads();
        short8 af0 = *(const short8*)&As[wrow + l16][quad * 8];
        short8 af1 = *(const short8*)&As[wrow + 16 + l16][quad * 8];
#pragma unroll
        for (int cg = 0; cg < CG; cg++) {
            short8 bf = *(const short8*)&Bs[wcol + cg * 16 + l16][quad * 8];
            acc[0][cg] = __builtin_amdgcn_mfma_f32_16x16x32_bf16(af0, bf, acc[0][cg], 0, 0, 0);
            acc[1][cg] = __builtin_amdgcn_mfma_f32_16x16x32_bf16(af1, bf, acc[1][cg], 0, 0, 0);
        }
        __syncthreads();
    }

    // epilogue: store bf16 H + fused partial logits
    float avs[CG], avd[CG];
#pragma unroll
    for (int cg = 0; cg < CG; cg++) {
        int gcol = wcol + cg * 16 + l16;
        avs[cg] = asrc[gcol];
        avd[cg] = adst[gcol];
#pragma unroll
        for (int rg = 0; rg < 2; rg++)
#pragma unroll
            for (int r = 0; r < 4; r++) {
                int grow = rowBase + wrow + rg * 16 + quad * 4 + r;
                H[(size_t)grow * NC + gcol] = f2b(acc[rg][cg][r]);
            }
    }
#pragma unroll
    for (int rg = 0; rg < 2; rg++)
#pragma unroll
        for (int r = 0; r < 4; r++) {
            float ps = 0.f, pd = 0.f;
#pragma unroll
            for (int cg = 0; cg < CG; cg++) { ps += acc[rg][cg][r] * avs[cg]; pd += acc[rg][cg][r] * avd[cg]; }
#pragma unroll
            for (int off = 8; off; off >>= 1) { ps += __shfl_xor(ps, off); pd += __shfl_xor(pd, off); }
            if (l16 == 0) {
                int lrow = wrow + rg * 16 + quad * 4 + r;
                atomicAdd(&sps[lrow], ps);
                atomicAdd(&spd[lrow], pd);
            }
        }
    __syncthreads();
    if (tid < 64) { als[rowBase + tid] = sps[tid]; ald[rowBase + tid] = spd[tid]; }
}

// ---------- edge softmax + weighted aggregation, one wave per dst node ----------
// No max-subtraction: logits are O(1) (|e| << 80), exp(e)/sum(exp(e)) is safe in fp32
// and identical (to rounding) to the max-shifted form. Single fused exp+sum pass.
// Pass 3 processes FOUR edges per iteration: 16-lane quarter q takes edge 4t+q.
template<int DOUT, bool RELU, typename OutT>
__global__ __launch_bounds__(256) void k_edge(const unsigned short* __restrict__ h,
                                              const float* __restrict__ als,
                                              const float* __restrict__ ald,
                                              const int* __restrict__ begptr,
                                              const int* __restrict__ cnt,
                                              const int* __restrict__ colidx,
                                              const float* __restrict__ bias,
                                              OutT* __restrict__ out, int N) {
    int node = blockIdx.x * 4 + (threadIdx.x >> 6);
    if (node >= N) return;
    int lane = threadIdx.x & 63;
    int beg = begptr[node];
    int deg = cnt[node] + 1;   // + self-loop
    float aldi = ald[node];

    // fused pass: exp + sum (lanes j<64 cache their edge's exp and src)
    float ex_lane = 0.f;
    int   s_lane = 0;
    float dsum = 0.f;
    for (int j = lane; j < deg; j += 64) {
        int s = colidx[beg + j];
        float e = als[s] + aldi;
        e = e > 0.f ? e : 0.2f * e;
        float ex = __expf(e);
        if (j < 64) { ex_lane = ex; s_lane = s; }
        dsum += ex;
    }
#pragma unroll
    for (int off = 32; off; off >>= 1) dsum += __shfl_xor(dsum, off);
    float inv = 1.0f / dsum;
    float w_lane = ex_lane * inv;      // lanes >= deg carry ex_lane == 0

    // pass 3: quad-edge weighted gather-accumulate (16-lane row quarters)
    constexpr int QV  = DOUT / 16;         // dims per lane (16 @ 256, 8 @ 128)
    constexpr int NC8 = QV / 8;            // u16x8 chunks per lane (2 or 1)
    const int l16g    = lane & 15;
    const int quarter = lane >> 4;
    const size_t dimOff = (size_t)l16g * QV;
    float acc[QV] = {};
    int lim = deg < 64 ? deg : 64;
    for (int t = 0; 4 * t < lim; t++) {
        int idx = 4 * t + quarter;         // idx >= deg -> wj == 0, load is safe (s_lane=0)
        float wj = __shfl(w_lane, idx);
        int   sj = __shfl(s_lane, idx);
        const unsigned short* hp = h + (size_t)sj * DOUT + dimOff;
        u16x8 c[NC8];
#pragma unroll
        for (int u = 0; u < NC8; u++) c[u] = *(const u16x8*)(hp + 8 * u);
#pragma unroll
        for (int u = 0; u < NC8; u++)
#pragma unroll
            for (int v = 0; v < 8; v++) acc[8 * u + v] += wj * b2f(c[u][v]);
    }
    for (int j = 64; j < deg; j++) {       // rare overflow path (deg>64): quarter 0 only
        int sj = colidx[beg + j];
        float e = als[sj] + aldi;
        e = e > 0.f ? e : 0.2f * e;
        float wj = __expf(e) * inv;
        if (quarter == 0) {
            const unsigned short* hp = h + (size_t)sj * DOUT + dimOff;
#pragma unroll
            for (int u = 0; u < NC8; u++) {
                u16x8 c = *(const u16x8*)(hp + 8 * u);
#pragma unroll
                for (int v = 0; v < 8; v++) acc[8 * u + v] += wj * b2f(c[v]);
            }
        }
    }
    // combine quarters: xor 16 then xor 32 -> every lane holds the full sum
#pragma unroll
    for (int v = 0; v < QV; v++) {
        acc[v] += __shfl_xor(acc[v], 16);
        acc[v] += __shfl_xor(acc[v], 32);
    }

    if (quarter == 0) {
        if constexpr (std::is_same_v<OutT, float>) {
            float* op = out + (size_t)node * DOUT + dimOff;
#pragma unroll
            for (int u = 0; u < QV / 4; u++) {
                f32x4 bv = *(const f32x4*)(bias + dimOff + 4 * u);
                f32x4 ov;
#pragma unroll
                for (int v = 0; v < 4; v++) {
                    float val = acc[4 * u + v] + bv[v];
                    if (RELU) val = fmaxf(val, 0.f);
                    ov[v] = val;
                }
                *(f32x4*)(op + 4 * u) = ov;
            }
        } else {
            unsigned short* op = out + (size_t)node * DOUT + dimOff;
#pragma unroll
            for (int u = 0; u < NC8; u++) {
                u16x8 ov;
#pragma unroll
                for (int v = 0; v < 8; v++) {
                    float val = acc[8 * u + v] + bias[dimOff + 8 * u + v];
                    if (RELU) val = fmaxf(val, 0.f);
                    ov[v] = f2b(val);
                }
                *(u16x8*)(op + 8 * u) = ov;
            }
        }
    }
}

// ---------- launch ----------
extern "C" void kernel_launch(void* const* d_in, const int* in_sizes, int n_in,
                              void* d_out, int out_size, void* d_ws, size_t ws_size,
                              hipStream_t stream) {
    const int DIN = 128, DH = 256, DOUT = 128;
    const int N = in_sizes[0] / DIN;        // 40000
    const int E = in_sizes[1] / 2;          // 400000

    const float* x   = (const float*)d_in[0];
    const int*   ei  = (const int*)d_in[1];
    const float* W1  = (const float*)d_in[3];
    const float* as1 = (const float*)d_in[4];
    const float* ad1 = (const float*)d_in[5];
    const float* b1  = (const float*)d_in[6];
    const float* W2  = (const float*)d_in[7];
    const float* as2 = (const float*)d_in[8];
    const float* ad2 = (const float*)d_in[9];
    const float* b2  = (const float*)d_in[10];
    const float* W3  = (const float*)d_in[11];
    const float* as3 = (const float*)d_in[12];
    const float* ad3 = (const float*)d_in[13];
    const float* b3  = (const float*)d_in[14];
    float* outp = (float*)d_out;

    // workspace carve
    char* ws = (char*)d_ws;
    size_t off = 0;
    auto carve = [&](size_t bytes) { char* p = ws + off; off = (off + bytes + 255) & ~(size_t)255; return p; };
    unsigned short* hbuf = (unsigned short*)carve((size_t)N * DH * 2);  // 20 MB bf16
    unsigned short* gbuf = (unsigned short*)carve((size_t)N * DH * 2);  // 20 MB bf16
    float* als  = (float*)carve((size_t)N * 4);
    float* ald  = (float*)carve((size_t)N * 4);
    unsigned short* wt1 = (unsigned short*)carve((size_t)DIN * DH * 2);
    unsigned short* wt2 = (unsigned short*)carve((size_t)DH * DH * 2);
    unsigned short* wt3 = (unsigned short*)carve((size_t)DH * DOUT * 2);
    int* cnt    = (int*)carve((size_t)N * 4);
    int* cursor = (int*)carve(256);
    int* begptr = (int*)carve((size_t)N * 4);
    int* fill   = (int*)carve((size_t)N * 4);
    int* colidx = (int*)carve((size_t)(E + N) * 4);
    (void)ws_size; (void)n_in; (void)out_size;

    const int* e_src = ei;
    const int* e_dst = ei + E;

    // zero cnt..cursor in one async memset (allowed under graph capture)
    hipMemsetAsync(cnt, 0, (size_t)((char*)cursor - (char*)cnt) + 4, stream);

    // all-weight transpose up front
    {
        int tot = DIN * DH + DH * DH + DH * DOUT;
        k_transpose3<<<(tot + 255) / 256, 256, 0, stream>>>(W1, wt1, W2, wt2, W3, wt3,
                                                            DIN, DH, DH, DH, DH, DOUT);
    }

    // CSR build (identical every call; segment order unimportant)
    k_hist<<<(E + 255) / 256, 256, 0, stream>>>(e_dst, cnt, E);
    k_assign<<<(N + 255) / 256, 256, 0, stream>>>(cnt, begptr, colidx, fill, cursor, N);
    k_scatter<<<(E + 255) / 256, 256, 0, stream>>>(e_src, e_dst, fill, colidx, E);

    const int nblk4 = (N + 3) / 4;
    const int mblk  = N / 64;

    // ---- layer 1: x[N,128] @ W1[128,256] ----
    k_gemm<256, float><<<mblk, 256, 0, stream>>>(x, wt1, hbuf, as1, ad1, als, ald, DIN);
    k_edge<256, true, unsigned short><<<nblk4, 256, 0, stream>>>(hbuf, als, ald, begptr, cnt, colidx, b1, gbuf, N);

    // ---- layer 2: g[N,256] @ W2[256,256] ----
    k_gemm<256, unsigned short><<<mblk, 256, 0, stream>>>(gbuf, wt2, hbuf, as2, ad2, als, ald, DH);
    k_edge<256, true, unsigned short><<<nblk4, 256, 0, stream>>>(hbuf, als, ald, begptr, cnt, colidx, b2, gbuf, N);

    // ---- layer 3: g[N,256] @ W3[256,128] ----
    k_gemm<128, unsigned short><<<mblk, 256, 0, stream>>>(gbuf, wt3, hbuf, as3, ad3, als, ald, DH);
    k_edge<128, false, float><<<nblk4, 256, 0, stream>>>(hbuf, als, ald, begptr, cnt, colidx, b3, outp, N);
}

// Round 9
// 292.584 us; speedup vs baseline: 1.5588x; 1.0307x over previous
//
#include <hip/hip_runtime.h>
#include <hip/hip_bf16.h>
#include <type_traits>

// ---------- types ----------
typedef __attribute__((ext_vector_type(8))) short short8;   // 8 bf16 (4 VGPRs) MFMA A/B frag
typedef __attribute__((ext_vector_type(4))) float f32x4;    // MFMA C/D frag / float4
typedef __attribute__((ext_vector_type(8))) unsigned short u16x8;

static __device__ __forceinline__ unsigned short f2b(float f) {
    unsigned int v = __float_as_uint(f);
    unsigned int r = (v + 0x7FFFu + ((v >> 16) & 1u)) >> 16;   // RNE
    return (unsigned short)r;
}
static __device__ __forceinline__ float b2f(unsigned short u) {
    return __uint_as_float(((unsigned int)u) << 16);
}

// ---------- fused: all-weights transpose+cast  ||  dst-degree histogram ----------
// blocks [0, tblk): transpose; blocks [tblk, ...): histogram. Independent work.
__global__ void k_pre(const float* __restrict__ w1, unsigned short* __restrict__ t1,
                      const float* __restrict__ w2, unsigned short* __restrict__ t2,
                      const float* __restrict__ w3, unsigned short* __restrict__ t3,
                      int K1, int N1, int K2, int N2, int K3, int N3,
                      const int* __restrict__ dst, int* __restrict__ cnt, int E, int tblk) {
    if ((int)blockIdx.x < tblk) {
        int i = blockIdx.x * 256 + threadIdx.x;
        int n1 = K1 * N1, n2 = K2 * N2, n3 = K3 * N3;
        if (i < n1) {
            int k = i / N1, n = i % N1;
            t1[n * K1 + k] = f2b(w1[i]);
        } else if (i < n1 + n2) {
            int j = i - n1, k = j / N2, n = j % N2;
            t2[n * K2 + k] = f2b(w2[j]);
        } else if (i < n1 + n2 + n3) {
            int j = i - n1 - n2, k = j / N3, n = j % N3;
            t3[n * K3 + k] = f2b(w3[j]);
        }
    } else {
        int e = (blockIdx.x - tblk) * 256 + threadIdx.x;
        if (e < E) atomicAdd(&cnt[dst[e]], 1);
    }
}

// per-node segment allocation: wave-scan of (cnt+1) + one atomicAdd per wave.
// Places the self-loop at slot 0; fill[i] holds the ABSOLUTE next write slot (beg+1).
__global__ void k_assign(const int* __restrict__ cnt, int* __restrict__ begptr,
                         int* __restrict__ colidx, int* __restrict__ fill,
                         int* __restrict__ cursor, int n) {
    int i = blockIdx.x * 256 + threadIdx.x;
    int lane = threadIdx.x & 63;
    int c = (i < n) ? cnt[i] + 1 : 0;
    int s = c;  // inclusive wave scan
#pragma unroll
    for (int off = 1; off < 64; off <<= 1) {
        int v = __shfl_up(s, off);
        if (lane >= off) s += v;
    }
    int wavesum = __shfl(s, 63);
    int base = 0;
    if (lane == 63) base = atomicAdd(cursor, wavesum);
    base = __shfl(base, 63);
    int beg = base + s - c;
    if (i < n) { begptr[i] = beg; colidx[beg] = i; fill[i] = beg + 1; }
}

// ---------- MFMA GEMM body (BK=64) + fused attention logits ----------
// H[M,NC] (bf16) = A[M,K] * Bt^T;  als/ald[row] = H[row,:] . asrc/adst (fp32 acc)
// 4 waves tiled 2x2 over the 64xNC block; BK=64 halves barrier count vs BK=32.
template<int NC, typename AT>
static __device__ __forceinline__ void gemm_body(const AT* __restrict__ A,
                                                 const unsigned short* __restrict__ Bt,
                                                 unsigned short* __restrict__ H,
                                                 const float* __restrict__ asrc,
                                                 const float* __restrict__ adst,
                                                 float* __restrict__ als,
                                                 float* __restrict__ ald,
                                                 int K, int blk) {
    __shared__ unsigned short As[64][72];   // 64 k-cols + 8 pad
    __shared__ unsigned short Bs[NC][72];
    __shared__ float sps[64], spd[64];
    const int tid  = threadIdx.x;
    const int lane = tid & 63;
    const int wv   = tid >> 6;
    const int rowBase = blk * 64;
    const int quad = lane >> 4;
    const int l16  = lane & 15;
    constexpr int CG = NC / 32;             // col-frags per wave
    const int wrow = (wv & 1) * 32;
    const int wcol = (wv >> 1) * (NC / 2);
    f32x4 acc[2][CG] = {};

    if (tid < 64) { sps[tid] = 0.f; spd[tid] = 0.f; }

    const int ar = tid >> 2;                // A staging row 0..63
    const int ak = (tid & 3) * 16;          // A staging k-chunk (16 elems)

    for (int kk = 0; kk < K; kk += 64) {
        // stage A (16 elems/thread)
        if constexpr (std::is_same_v<AT, float>) {
            const float* ap = A + (size_t)(rowBase + ar) * K + kk + ak;
            f32x4 a0 = *(const f32x4*)ap;
            f32x4 a1 = *(const f32x4*)(ap + 4);
            f32x4 a2 = *(const f32x4*)(ap + 8);
            f32x4 a3 = *(const f32x4*)(ap + 12);
            short8 s0, s1;
#pragma unroll
            for (int v = 0; v < 4; v++) {
                s0[v] = (short)f2b(a0[v]); s0[4 + v] = (short)f2b(a1[v]);
                s1[v] = (short)f2b(a2[v]); s1[4 + v] = (short)f2b(a3[v]);
            }
            *(short8*)&As[ar][ak] = s0;
            *(short8*)&As[ar][ak + 8] = s1;
        } else {
            const unsigned short* ap = A + (size_t)(rowBase + ar) * K + kk + ak;
            *(short8*)&As[ar][ak]     = *(const short8*)ap;
            *(short8*)&As[ar][ak + 8] = *(const short8*)(ap + 8);
        }
        // stage B (chunks of 16)
#pragma unroll
        for (int c = tid; c < NC * 4; c += 256) {
            int br = c >> 2, bk = (c & 3) * 16;
            const unsigned short* bp = Bt + (size_t)br * K + kk + bk;
            *(short8*)&Bs[br][bk]     = *(const short8*)bp;
            *(short8*)&Bs[br][bk + 8] = *(const short8*)(bp + 8);
        }
        __syncthreads();
#pragma unroll
        for (int s = 0; s < 2; s++) {
            short8 af0 = *(const short8*)&As[wrow + l16][s * 32 + quad * 8];
            short8 af1 = *(const short8*)&As[wrow + 16 + l16][s * 32 + quad * 8];
#pragma unroll
            for (int cg = 0; cg < CG; cg++) {
                short8 bf = *(const short8*)&Bs[wcol + cg * 16 + l16][s * 32 + quad * 8];
                acc[0][cg] = __builtin_amdgcn_mfma_f32_16x16x32_bf16(af0, bf, acc[0][cg], 0, 0, 0);
                acc[1][cg] = __builtin_amdgcn_mfma_f32_16x16x32_bf16(af1, bf, acc[1][cg], 0, 0, 0);
            }
        }
        __syncthreads();
    }

    // epilogue: store bf16 H + fused partial logits
    float avs[CG], avd[CG];
#pragma unroll
    for (int cg = 0; cg < CG; cg++) {
        int gcol = wcol + cg * 16 + l16;
        avs[cg] = asrc[gcol];
        avd[cg] = adst[gcol];
#pragma unroll
        for (int rg = 0; rg < 2; rg++)
#pragma unroll
            for (int r = 0; r < 4; r++) {
                int grow = rowBase + wrow + rg * 16 + quad * 4 + r;
                H[(size_t)grow * NC + gcol] = f2b(acc[rg][cg][r]);
            }
    }
#pragma unroll
    for (int rg = 0; rg < 2; rg++)
#pragma unroll
        for (int r = 0; r < 4; r++) {
            float ps = 0.f, pd = 0.f;
#pragma unroll
            for (int cg = 0; cg < CG; cg++) { ps += acc[rg][cg][r] * avs[cg]; pd += acc[rg][cg][r] * avd[cg]; }
#pragma unroll
            for (int off = 8; off; off >>= 1) { ps += __shfl_xor(ps, off); pd += __shfl_xor(pd, off); }
            if (l16 == 0) {
                int lrow = wrow + rg * 16 + quad * 4 + r;
                atomicAdd(&sps[lrow], ps);
                atomicAdd(&spd[lrow], pd);
            }
        }
    __syncthreads();
    if (tid < 64) { als[rowBase + tid] = sps[tid]; ald[rowBase + tid] = spd[tid]; }
}

// plain GEMM kernel (layers 2,3)
template<int NC, typename AT>
__global__ __launch_bounds__(256) void k_gemm(const AT* __restrict__ A,
                                              const unsigned short* __restrict__ Bt,
                                              unsigned short* __restrict__ H,
                                              const float* __restrict__ asrc,
                                              const float* __restrict__ adst,
                                              float* __restrict__ als,
                                              float* __restrict__ ald, int K) {
    gemm_body<NC, AT>(A, Bt, H, asrc, adst, als, ald, K, blockIdx.x);
}

// fused: layer-1 GEMM || edge scatter (independent; both must finish before k_edge layer 1)
template<int NC, typename AT>
__global__ __launch_bounds__(256) void k_gemm_scatter(const AT* __restrict__ A,
                                                      const unsigned short* __restrict__ Bt,
                                                      unsigned short* __restrict__ H,
                                                      const float* __restrict__ asrc,
                                                      const float* __restrict__ adst,
                                                      float* __restrict__ als,
                                                      float* __restrict__ ald, int K, int gblk,
                                                      const int* __restrict__ src,
                                                      const int* __restrict__ dst,
                                                      int* __restrict__ fill,
                                                      int* __restrict__ colidx, int E) {
    if ((int)blockIdx.x < gblk) {
        gemm_body<NC, AT>(A, Bt, H, asrc, adst, als, ald, K, blockIdx.x);
    } else {
        int e = (blockIdx.x - gblk) * 256 + threadIdx.x;
        if (e < E) {
            int s = src[e], d = dst[e];
            int pos = atomicAdd(&fill[d], 1);
            colidx[pos] = s;
        }
    }
}

// ---------- edge softmax + weighted aggregation, one wave per dst node ----------
// No max-subtraction (logits O(1), fp32-safe). Pass 3: FOUR edges/iter, 16-lane row quarters.
template<int DOUT, bool RELU, typename OutT>
__global__ __launch_bounds__(256) void k_edge(const unsigned short* __restrict__ h,
                                              const float* __restrict__ als,
                                              const float* __restrict__ ald,
                                              const int* __restrict__ begptr,
                                              const int* __restrict__ cnt,
                                              const int* __restrict__ colidx,
                                              const float* __restrict__ bias,
                                              OutT* __restrict__ out, int N) {
    int node = blockIdx.x * 4 + (threadIdx.x >> 6);
    if (node >= N) return;
    int lane = threadIdx.x & 63;
    int beg = begptr[node];
    int deg = cnt[node] + 1;   // + self-loop
    float aldi = ald[node];

    // fused pass: exp + sum (lanes j<64 cache their edge's exp and src)
    float ex_lane = 0.f;
    int   s_lane = 0;
    float dsum = 0.f;
    for (int j = lane; j < deg; j += 64) {
        int s = colidx[beg + j];
        float e = als[s] + aldi;
        e = e > 0.f ? e : 0.2f * e;
        float ex = __expf(e);
        if (j < 64) { ex_lane = ex; s_lane = s; }
        dsum += ex;
    }
#pragma unroll
    for (int off = 32; off; off >>= 1) dsum += __shfl_xor(dsum, off);
    float inv = 1.0f / dsum;
    float w_lane = ex_lane * inv;      // lanes >= deg carry ex_lane == 0

    // pass 3: quad-edge weighted gather-accumulate (16-lane row quarters)
    constexpr int QV  = DOUT / 16;         // dims per lane (16 @ 256, 8 @ 128)
    constexpr int NC8 = QV / 8;            // u16x8 chunks per lane (2 or 1)
    const int l16g    = lane & 15;
    const int quarter = lane >> 4;
    const size_t dimOff = (size_t)l16g * QV;
    float acc[QV] = {};
    int lim = deg < 64 ? deg : 64;
    for (int t = 0; 4 * t < lim; t++) {
        int idx = 4 * t + quarter;         // idx >= deg -> wj == 0, load is safe (s_lane=0)
        float wj = __shfl(w_lane, idx);
        int   sj = __shfl(s_lane, idx);
        const unsigned short* hp = h + (size_t)sj * DOUT + dimOff;
        u16x8 c[NC8];
#pragma unroll
        for (int u = 0; u < NC8; u++) c[u] = *(const u16x8*)(hp + 8 * u);
#pragma unroll
        for (int u = 0; u < NC8; u++)
#pragma unroll
            for (int v = 0; v < 8; v++) acc[8 * u + v] += wj * b2f(c[u][v]);
    }
    for (int j = 64; j < deg; j++) {       // rare overflow path (deg>64): quarter 0 only
        int sj = colidx[beg + j];
        float e = als[sj] + aldi;
        e = e > 0.f ? e : 0.2f * e;
        float wj = __expf(e) * inv;
        if (quarter == 0) {
            const unsigned short* hp = h + (size_t)sj * DOUT + dimOff;
#pragma unroll
            for (int u = 0; u < NC8; u++) {
                u16x8 c = *(const u16x8*)(hp + 8 * u);
#pragma unroll
                for (int v = 0; v < 8; v++) acc[8 * u + v] += wj * b2f(c[v]);
            }
        }
    }
    // combine quarters
#pragma unroll
    for (int v = 0; v < QV; v++) {
        acc[v] += __shfl_xor(acc[v], 16);
        acc[v] += __shfl_xor(acc[v], 32);
    }

    if (quarter == 0) {
        if constexpr (std::is_same_v<OutT, float>) {
            float* op = out + (size_t)node * DOUT + dimOff;
#pragma unroll
            for (int u = 0; u < QV / 4; u++) {
                f32x4 bv = *(const f32x4*)(bias + dimOff + 4 * u);
                f32x4 ov;
#pragma unroll
                for (int v = 0; v < 4; v++) {
                    float val = acc[4 * u + v] + bv[v];
                    if (RELU) val = fmaxf(val, 0.f);
                    ov[v] = val;
                }
                *(f32x4*)(op + 4 * u) = ov;
            }
        } else {
            unsigned short* op = out + (size_t)node * DOUT + dimOff;
#pragma unroll
            for (int u = 0; u < NC8; u++) {
                u16x8 ov;
#pragma unroll
                for (int v = 0; v < 8; v++) {
                    float val = acc[8 * u + v] + bias[dimOff + 8 * u + v];
                    if (RELU) val = fmaxf(val, 0.f);
                    ov[v] = f2b(val);
                }
                *(u16x8*)(op + 8 * u) = ov;
            }
        }
    }
}

// ---------- launch ----------
extern "C" void kernel_launch(void* const* d_in, const int* in_sizes, int n_in,
                              void* d_out, int out_size, void* d_ws, size_t ws_size,
                              hipStream_t stream) {
    const int DIN = 128, DH = 256, DOUT = 128;
    const int N = in_sizes[0] / DIN;        // 40000
    const int E = in_sizes[1] / 2;          // 400000

    const float* x   = (const float*)d_in[0];
    const int*   ei  = (const int*)d_in[1];
    const float* W1  = (const float*)d_in[3];
    const float* as1 = (const float*)d_in[4];
    const float* ad1 = (const float*)d_in[5];
    const float* b1  = (const float*)d_in[6];
    const float* W2  = (const float*)d_in[7];
    const float* as2 = (const float*)d_in[8];
    const float* ad2 = (const float*)d_in[9];
    const float* b2  = (const float*)d_in[10];
    const float* W3  = (const float*)d_in[11];
    const float* as3 = (const float*)d_in[12];
    const float* ad3 = (const float*)d_in[13];
    const float* b3  = (const float*)d_in[14];
    float* outp = (float*)d_out;

    // workspace carve
    char* ws = (char*)d_ws;
    size_t off = 0;
    auto carve = [&](size_t bytes) { char* p = ws + off; off = (off + bytes + 255) & ~(size_t)255; return p; };
    unsigned short* hbuf = (unsigned short*)carve((size_t)N * DH * 2);  // 20 MB bf16
    unsigned short* gbuf = (unsigned short*)carve((size_t)N * DH * 2);  // 20 MB bf16
    float* als  = (float*)carve((size_t)N * 4);
    float* ald  = (float*)carve((size_t)N * 4);
    unsigned short* wt1 = (unsigned short*)carve((size_t)DIN * DH * 2);
    unsigned short* wt2 = (unsigned short*)carve((size_t)DH * DH * 2);
    unsigned short* wt3 = (unsigned short*)carve((size_t)DH * DOUT * 2);
    int* cnt    = (int*)carve((size_t)N * 4);
    int* cursor = (int*)carve(256);
    int* begptr = (int*)carve((size_t)N * 4);
    int* fill   = (int*)carve((size_t)N * 4);
    int* colidx = (int*)carve((size_t)(E + N) * 4);
    (void)ws_size; (void)n_in; (void)out_size;

    const int* e_src = ei;
    const int* e_dst = ei + E;

    // zero cnt..cursor in one async memset (allowed under graph capture)
    hipMemsetAsync(cnt, 0, (size_t)((char*)cursor - (char*)cnt) + 4, stream);

    const int tot   = DIN * DH + DH * DH + DH * DOUT;   // transpose elements
    const int tblk  = (tot + 255) / 256;
    const int eblk  = (E + 255) / 256;
    const int nblk4 = (N + 3) / 4;
    const int mblk  = N / 64;

    // transpose+cast all weights  ||  degree histogram
    k_pre<<<tblk + eblk, 256, 0, stream>>>(W1, wt1, W2, wt2, W3, wt3,
                                           DIN, DH, DH, DH, DH, DOUT,
                                           e_dst, cnt, E, tblk);
    k_assign<<<(N + 255) / 256, 256, 0, stream>>>(cnt, begptr, colidx, fill, cursor, N);

    // ---- layer 1 GEMM || edge scatter ----
    k_gemm_scatter<256, float><<<mblk + eblk, 256, 0, stream>>>(
        x, wt1, hbuf, as1, ad1, als, ald, DIN, mblk,
        e_src, e_dst, fill, colidx, E);
    k_edge<256, true, unsigned short><<<nblk4, 256, 0, stream>>>(hbuf, als, ald, begptr, cnt, colidx, b1, gbuf, N);

    // ---- layer 2: g[N,256] @ W2[256,256] ----
    k_gemm<256, unsigned short><<<mblk, 256, 0, stream>>>(gbuf, wt2, hbuf, as2, ad2, als, ald, DH);
    k_edge<256, true, unsigned short><<<nblk4, 256, 0, stream>>>(hbuf, als, ald, begptr, cnt, colidx, b2, gbuf, N);

    // ---- layer 3: g[N,256] @ W3[256,128] ----
    k_gemm<128, unsigned short><<<mblk, 256, 0, stream>>>(gbuf, wt3, hbuf, as3, ad3, als, ald, DH);
    k_edge<128, false, float><<<nblk4, 256, 0, stream>>>(hbuf, als, ald, begptr, cnt, colidx, b3, outp, N);
}

// Round 10
// 286.498 us; speedup vs baseline: 1.5919x; 1.0212x over previous
//
#include <hip/hip_runtime.h>
#include <hip/hip_bf16.h>
#include <type_traits>

// ---------- types ----------
typedef __attribute__((ext_vector_type(8))) short short8;   // 8 bf16 (4 VGPRs) MFMA A/B frag
typedef __attribute__((ext_vector_type(4))) float f32x4;    // MFMA C/D frag / float4
typedef __attribute__((ext_vector_type(8))) unsigned short u16x8;

static __device__ __forceinline__ unsigned short f2b(float f) {
    unsigned int v = __float_as_uint(f);
    unsigned int r = (v + 0x7FFFu + ((v >> 16) & 1u)) >> 16;   // RNE
    return (unsigned short)r;
}
static __device__ __forceinline__ float b2f(unsigned short u) {
    return __uint_as_float(((unsigned int)u) << 16);
}

// ---------- fused: all-weights transpose+cast  ||  dst-degree histogram ----------
__global__ void k_pre(const float* __restrict__ w1, unsigned short* __restrict__ t1,
                      const float* __restrict__ w2, unsigned short* __restrict__ t2,
                      const float* __restrict__ w3, unsigned short* __restrict__ t3,
                      int K1, int N1, int K2, int N2, int K3, int N3,
                      const int* __restrict__ dst, int* __restrict__ cnt, int E, int tblk) {
    if ((int)blockIdx.x < tblk) {
        int i = blockIdx.x * 256 + threadIdx.x;
        int n1 = K1 * N1, n2 = K2 * N2, n3 = K3 * N3;
        if (i < n1) {
            int k = i / N1, n = i % N1;
            t1[n * K1 + k] = f2b(w1[i]);
        } else if (i < n1 + n2) {
            int j = i - n1, k = j / N2, n = j % N2;
            t2[n * K2 + k] = f2b(w2[j]);
        } else if (i < n1 + n2 + n3) {
            int j = i - n1 - n2, k = j / N3, n = j % N3;
            t3[n * K3 + k] = f2b(w3[j]);
        }
    } else {
        int e = (blockIdx.x - tblk) * 256 + threadIdx.x;
        if (e < E) atomicAdd(&cnt[dst[e]], 1);
    }
}

// per-node segment allocation: wave-scan of (cnt+1) + one atomicAdd per wave.
// Places the self-loop at slot 0; fill[i] holds the ABSOLUTE next write slot (beg+1).
__global__ void k_assign(const int* __restrict__ cnt, int* __restrict__ begptr,
                         int* __restrict__ colidx, int* __restrict__ fill,
                         int* __restrict__ cursor, int n) {
    int i = blockIdx.x * 256 + threadIdx.x;
    int lane = threadIdx.x & 63;
    int c = (i < n) ? cnt[i] + 1 : 0;
    int s = c;  // inclusive wave scan
#pragma unroll
    for (int off = 1; off < 64; off <<= 1) {
        int v = __shfl_up(s, off);
        if (lane >= off) s += v;
    }
    int wavesum = __shfl(s, 63);
    int base = 0;
    if (lane == 63) base = atomicAdd(cursor, wavesum);
    base = __shfl(base, 63);
    int beg = base + s - c;
    if (i < n) { begptr[i] = beg; colidx[beg] = i; fill[i] = beg + 1; }
}

// ---------- MFMA GEMM body (BK=64) + fused attention logits ----------
template<int NC, typename AT>
static __device__ __forceinline__ void gemm_body(const AT* __restrict__ A,
                                                 const unsigned short* __restrict__ Bt,
                                                 unsigned short* __restrict__ H,
                                                 const float* __restrict__ asrc,
                                                 const float* __restrict__ adst,
                                                 float* __restrict__ als,
                                                 float* __restrict__ ald,
                                                 int K, int blk) {
    __shared__ unsigned short As[64][72];   // 64 k-cols + 8 pad
    __shared__ unsigned short Bs[NC][72];
    __shared__ float sps[64], spd[64];
    const int tid  = threadIdx.x;
    const int lane = tid & 63;
    const int wv   = tid >> 6;
    const int rowBase = blk * 64;
    const int quad = lane >> 4;
    const int l16  = lane & 15;
    constexpr int CG = NC / 32;             // col-frags per wave
    const int wrow = (wv & 1) * 32;
    const int wcol = (wv >> 1) * (NC / 2);
    f32x4 acc[2][CG] = {};

    if (tid < 64) { sps[tid] = 0.f; spd[tid] = 0.f; }

    const int ar = tid >> 2;                // A staging row 0..63
    const int ak = (tid & 3) * 16;          // A staging k-chunk (16 elems)

    for (int kk = 0; kk < K; kk += 64) {
        // stage A (16 elems/thread)
        if constexpr (std::is_same_v<AT, float>) {
            const float* ap = A + (size_t)(rowBase + ar) * K + kk + ak;
            f32x4 a0 = *(const f32x4*)ap;
            f32x4 a1 = *(const f32x4*)(ap + 4);
            f32x4 a2 = *(const f32x4*)(ap + 8);
            f32x4 a3 = *(const f32x4*)(ap + 12);
            short8 s0, s1;
#pragma unroll
            for (int v = 0; v < 4; v++) {
                s0[v] = (short)f2b(a0[v]); s0[4 + v] = (short)f2b(a1[v]);
                s1[v] = (short)f2b(a2[v]); s1[4 + v] = (short)f2b(a3[v]);
            }
            *(short8*)&As[ar][ak] = s0;
            *(short8*)&As[ar][ak + 8] = s1;
        } else {
            const unsigned short* ap = A + (size_t)(rowBase + ar) * K + kk + ak;
            *(short8*)&As[ar][ak]     = *(const short8*)ap;
            *(short8*)&As[ar][ak + 8] = *(const short8*)(ap + 8);
        }
        // stage B (chunks of 16)
#pragma unroll
        for (int c = tid; c < NC * 4; c += 256) {
            int br = c >> 2, bk = (c & 3) * 16;
            const unsigned short* bp = Bt + (size_t)br * K + kk + bk;
            *(short8*)&Bs[br][bk]     = *(const short8*)bp;
            *(short8*)&Bs[br][bk + 8] = *(const short8*)(bp + 8);
        }
        __syncthreads();
#pragma unroll
        for (int s = 0; s < 2; s++) {
            short8 af0 = *(const short8*)&As[wrow + l16][s * 32 + quad * 8];
            short8 af1 = *(const short8*)&As[wrow + 16 + l16][s * 32 + quad * 8];
#pragma unroll
            for (int cg = 0; cg < CG; cg++) {
                short8 bf = *(const short8*)&Bs[wcol + cg * 16 + l16][s * 32 + quad * 8];
                acc[0][cg] = __builtin_amdgcn_mfma_f32_16x16x32_bf16(af0, bf, acc[0][cg], 0, 0, 0);
                acc[1][cg] = __builtin_amdgcn_mfma_f32_16x16x32_bf16(af1, bf, acc[1][cg], 0, 0, 0);
            }
        }
        __syncthreads();
    }

    // epilogue: store bf16 H + fused partial logits
    float avs[CG], avd[CG];
#pragma unroll
    for (int cg = 0; cg < CG; cg++) {
        int gcol = wcol + cg * 16 + l16;
        avs[cg] = asrc[gcol];
        avd[cg] = adst[gcol];
#pragma unroll
        for (int rg = 0; rg < 2; rg++)
#pragma unroll
            for (int r = 0; r < 4; r++) {
                int grow = rowBase + wrow + rg * 16 + quad * 4 + r;
                H[(size_t)grow * NC + gcol] = f2b(acc[rg][cg][r]);
            }
    }
#pragma unroll
    for (int rg = 0; rg < 2; rg++)
#pragma unroll
        for (int r = 0; r < 4; r++) {
            float ps = 0.f, pd = 0.f;
#pragma unroll
            for (int cg = 0; cg < CG; cg++) { ps += acc[rg][cg][r] * avs[cg]; pd += acc[rg][cg][r] * avd[cg]; }
#pragma unroll
            for (int off = 8; off; off >>= 1) { ps += __shfl_xor(ps, off); pd += __shfl_xor(pd, off); }
            if (l16 == 0) {
                int lrow = wrow + rg * 16 + quad * 4 + r;
                atomicAdd(&sps[lrow], ps);
                atomicAdd(&spd[lrow], pd);
            }
        }
    __syncthreads();
    if (tid < 64) { als[rowBase + tid] = sps[tid]; ald[rowBase + tid] = spd[tid]; }
}

// plain GEMM kernel (layers 2,3)
template<int NC, typename AT>
__global__ __launch_bounds__(256) void k_gemm(const AT* __restrict__ A,
                                              const unsigned short* __restrict__ Bt,
                                              unsigned short* __restrict__ H,
                                              const float* __restrict__ asrc,
                                              const float* __restrict__ adst,
                                              float* __restrict__ als,
                                              float* __restrict__ ald, int K) {
    gemm_body<NC, AT>(A, Bt, H, asrc, adst, als, ald, K, blockIdx.x);
}

// fused: layer-1 GEMM || edge scatter
template<int NC, typename AT>
__global__ __launch_bounds__(256) void k_gemm_scatter(const AT* __restrict__ A,
                                                      const unsigned short* __restrict__ Bt,
                                                      unsigned short* __restrict__ H,
                                                      const float* __restrict__ asrc,
                                                      const float* __restrict__ adst,
                                                      float* __restrict__ als,
                                                      float* __restrict__ ald, int K, int gblk,
                                                      const int* __restrict__ src,
                                                      const int* __restrict__ dst,
                                                      int* __restrict__ fill,
                                                      int* __restrict__ colidx, int E) {
    if ((int)blockIdx.x < gblk) {
        gemm_body<NC, AT>(A, Bt, H, asrc, adst, als, ald, K, blockIdx.x);
    } else {
        int e = (blockIdx.x - gblk) * 256 + threadIdx.x;
        if (e < E) {
            int s = src[e], d = dst[e];
            int pos = atomicAdd(&fill[d], 1);
            colidx[pos] = s;
        }
    }
}

// ---------- edge softmax + weighted aggregation: ONE NODE PER 16-LANE QUARTER ----------
// 4 nodes/wave, 16 nodes/block. Phase 1 (exp+sum) runs for 4 nodes in parallel
// (width-16 reduce); pass 3: each quarter walks its node's edges, lanes cover
// DOUT/16 dims (32B @ 256). No cross-quarter combine — quarter owns its node.
// No max-subtraction (logits O(1), fp32-safe).
template<int DOUT, bool RELU, typename OutT>
__global__ __launch_bounds__(256) void k_edge(const unsigned short* __restrict__ h,
                                              const float* __restrict__ als,
                                              const float* __restrict__ ald,
                                              const int* __restrict__ begptr,
                                              const int* __restrict__ cnt,
                                              const int* __restrict__ colidx,
                                              const float* __restrict__ bias,
                                              OutT* __restrict__ out, int N) {
    int node = blockIdx.x * 16 + (threadIdx.x >> 4);
    if (node >= N) return;
    int lane  = threadIdx.x & 63;
    int l16   = lane & 15;
    int qbase = lane & 48;                  // quarter base within wave
    int beg = begptr[node];
    int deg = cnt[node] + 1;                // + self-loop
    float aldi = ald[node];

    // phase 1: exp + sum over this quarter's 16 lanes (first 16 edges cached)
    float ex_lane = 0.f;
    int   s_lane  = 0;
    float dsum = 0.f;
    for (int j = l16; j < deg; j += 16) {
        int s = colidx[beg + j];
        float e = als[s] + aldi;
        e = e > 0.f ? e : 0.2f * e;
        float ex = __expf(e);
        if (j < 16) { ex_lane = ex; s_lane = s; }
        dsum += ex;
    }
#pragma unroll
    for (int off = 8; off; off >>= 1) dsum += __shfl_xor(dsum, off, 16);
    float inv = 1.0f / dsum;
    float w_lane = ex_lane * inv;           // lanes >= deg carry 0

    // wave-uniform loop bounds (max over the wave's 4 quarters)
    int d16 = deg < 16 ? deg : 16;
    int m16 = d16;
    m16 = max(m16, __shfl_xor(m16, 16));
    m16 = max(m16, __shfl_xor(m16, 32));
    int mall = deg;
    mall = max(mall, __shfl_xor(mall, 16));
    mall = max(mall, __shfl_xor(mall, 32));

    constexpr int QV  = DOUT / 16;          // dims per lane (16 @ 256, 8 @ 128)
    constexpr int NC8 = QV / 8;             // u16x8 chunks per lane (2 or 1)
    const size_t dimOff = (size_t)l16 * QV;
    float acc[QV] = {};

    for (int t = 0; t < m16; t++) {
        float wj = __shfl(w_lane, qbase + t);   // all lanes active for the shfl
        int   sj = __shfl(s_lane, qbase + t);
        if (wj != 0.f) {                        // t >= deg -> wj == 0 -> skip load
            const unsigned short* hp = h + (size_t)sj * DOUT + dimOff;
            u16x8 c[NC8];
#pragma unroll
            for (int u = 0; u < NC8; u++) c[u] = *(const u16x8*)(hp + 8 * u);
#pragma unroll
            for (int u = 0; u < NC8; u++)
#pragma unroll
                for (int v = 0; v < 8; v++) acc[8 * u + v] += wj * b2f(c[u][v]);
        }
    }
    for (int t = 16; t < mall; t++) {           // deg>16 tail (~5% of nodes): recompute w
        if (t < deg) {
            int sj = colidx[beg + t];
            float e = als[sj] + aldi;
            e = e > 0.f ? e : 0.2f * e;
            float wj = __expf(e) * inv;
            const unsigned short* hp = h + (size_t)sj * DOUT + dimOff;
#pragma unroll
            for (int u = 0; u < NC8; u++) {
                u16x8 c = *(const u16x8*)(hp + 8 * u);
#pragma unroll
                for (int v = 0; v < 8; v++) acc[8 * u + v] += wj * b2f(c[v]);
            }
        }
    }

    // epilogue: every lane writes its QV dims of its quarter's node
    if constexpr (std::is_same_v<OutT, float>) {
        float* op = out + (size_t)node * DOUT + dimOff;
#pragma unroll
        for (int u = 0; u < QV / 4; u++) {
            f32x4 bv = *(const f32x4*)(bias + dimOff + 4 * u);
            f32x4 ov;
#pragma unroll
            for (int v = 0; v < 4; v++) {
                float val = acc[4 * u + v] + bv[v];
                if (RELU) val = fmaxf(val, 0.f);
                ov[v] = val;
            }
            *(f32x4*)(op + 4 * u) = ov;
        }
    } else {
        unsigned short* op = out + (size_t)node * DOUT + dimOff;
#pragma unroll
        for (int u = 0; u < NC8; u++) {
            u16x8 ov;
#pragma unroll
            for (int v = 0; v < 8; v++) {
                float val = acc[8 * u + v] + bias[dimOff + 8 * u + v];
                if (RELU) val = fmaxf(val, 0.f);
                ov[v] = f2b(val);
            }
            *(u16x8*)(op + 8 * u) = ov;
        }
    }
}

// ---------- launch ----------
extern "C" void kernel_launch(void* const* d_in, const int* in_sizes, int n_in,
                              void* d_out, int out_size, void* d_ws, size_t ws_size,
                              hipStream_t stream) {
    const int DIN = 128, DH = 256, DOUT = 128;
    const int N = in_sizes[0] / DIN;        // 40000
    const int E = in_sizes[1] / 2;          // 400000

    const float* x   = (const float*)d_in[0];
    const int*   ei  = (const int*)d_in[1];
    const float* W1  = (const float*)d_in[3];
    const float* as1 = (const float*)d_in[4];
    const float* ad1 = (const float*)d_in[5];
    const float* b1  = (const float*)d_in[6];
    const float* W2  = (const float*)d_in[7];
    const float* as2 = (const float*)d_in[8];
    const float* ad2 = (const float*)d_in[9];
    const float* b2  = (const float*)d_in[10];
    const float* W3  = (const float*)d_in[11];
    const float* as3 = (const float*)d_in[12];
    const float* ad3 = (const float*)d_in[13];
    const float* b3  = (const float*)d_in[14];
    float* outp = (float*)d_out;

    // workspace carve
    char* ws = (char*)d_ws;
    size_t off = 0;
    auto carve = [&](size_t bytes) { char* p = ws + off; off = (off + bytes + 255) & ~(size_t)255; return p; };
    unsigned short* hbuf = (unsigned short*)carve((size_t)N * DH * 2);  // 20 MB bf16
    unsigned short* gbuf = (unsigned short*)carve((size_t)N * DH * 2);  // 20 MB bf16
    float* als  = (float*)carve((size_t)N * 4);
    float* ald  = (float*)carve((size_t)N * 4);
    unsigned short* wt1 = (unsigned short*)carve((size_t)DIN * DH * 2);
    unsigned short* wt2 = (unsigned short*)carve((size_t)DH * DH * 2);
    unsigned short* wt3 = (unsigned short*)carve((size_t)DH * DOUT * 2);
    int* cnt    = (int*)carve((size_t)N * 4);
    int* cursor = (int*)carve(256);
    int* begptr = (int*)carve((size_t)N * 4);
    int* fill   = (int*)carve((size_t)N * 4);
    int* colidx = (int*)carve((size_t)(E + N) * 4);
    (void)ws_size; (void)n_in; (void)out_size;

    const int* e_src = ei;
    const int* e_dst = ei + E;

    // zero cnt..cursor in one async memset (allowed under graph capture)
    hipMemsetAsync(cnt, 0, (size_t)((char*)cursor - (char*)cnt) + 4, stream);

    const int tot    = DIN * DH + DH * DH + DH * DOUT;   // transpose elements
    const int tblk   = (tot + 255) / 256;
    const int eblk   = (E + 255) / 256;
    const int nblk16 = (N + 15) / 16;
    const int mblk   = N / 64;

    // transpose+cast all weights  ||  degree histogram
    k_pre<<<tblk + eblk, 256, 0, stream>>>(W1, wt1, W2, wt2, W3, wt3,
                                           DIN, DH, DH, DH, DH, DOUT,
                                           e_dst, cnt, E, tblk);
    k_assign<<<(N + 255) / 256, 256, 0, stream>>>(cnt, begptr, colidx, fill, cursor, N);

    // ---- layer 1 GEMM || edge scatter ----
    k_gemm_scatter<256, float><<<mblk + eblk, 256, 0, stream>>>(
        x, wt1, hbuf, as1, ad1, als, ald, DIN, mblk,
        e_src, e_dst, fill, colidx, E);
    k_edge<256, true, unsigned short><<<nblk16, 256, 0, stream>>>(hbuf, als, ald, begptr, cnt, colidx, b1, gbuf, N);

    // ---- layer 2: g[N,256] @ W2[256,256] ----
    k_gemm<256, unsigned short><<<mblk, 256, 0, stream>>>(gbuf, wt2, hbuf, as2, ad2, als, ald, DH);
    k_edge<256, true, unsigned short><<<nblk16, 256, 0, stream>>>(hbuf, als, ald, begptr, cnt, colidx, b2, gbuf, N);

    // ---- layer 3: g[N,256] @ W3[256,128] ----
    k_gemm<128, unsigned short><<<mblk, 256, 0, stream>>>(gbuf, wt3, hbuf, as3, ad3, als, ald, DH);
    k_edge<128, false, float><<<nblk16, 256, 0, stream>>>(hbuf, als, ald, begptr, cnt, colidx, b3, outp, N);
}